// Round 3
// baseline (1811.040 us; speedup 1.0000x reference)
//
#include <hip/hip_runtime.h>
#include <cmath>

typedef __bf16 bf16;
typedef __attribute__((ext_vector_type(8))) __bf16 bf16x8;
typedef __attribute__((ext_vector_type(4))) __bf16 bf16x4;
typedef __attribute__((ext_vector_type(4))) float f32x4;

#define NB 2
#define NSEQ 2048
#define NDIM 512
#define NHEADS 8
#define DHEAD 64
#define NMEM 16
#define NJ 2064
#define NJP 2176        // 17*128
#define NFF 2048
#define NROWS (NB*NSEQ) // 4096

enum { EPI_F32 = 0, EPI_DOTS = 1, EPI_SPLIT = 2, EPI_GELUSPLIT = 3, EPI_RESID = 4 };

// ---------------------------------------------------------------------------
// Split-precision GEMM: fp32 operands stored as bf16 (hi,lo): cols [0,K)=hi,
// [K,2K)=lo. C = Ah*Bh + Al*Bh + Ah*Bl (3 MFMAs, fp32 accum), rel err ~4e-6.
// ---------------------------------------------------------------------------
template<int BM, int BN, int WAVES_M, int WAVES_N, int EPI>
__global__ __launch_bounds__(256)
void gemm_split(const bf16* __restrict__ A, const bf16* __restrict__ B,
                void* __restrict__ Cv, const float* __restrict__ bias,
                int K, int lda, int ldb, int ldc,
                long long sAz, long long sBz, long long sCz, int kh0)
{
  constexpr int BK = 32;
  constexpr int WM = BM / WAVES_M;
  constexpr int WN = BN / WAVES_N;
  constexpr int MF = WM / 16;
  constexpr int NF = WN / 16;
  constexpr int AI = (BM * BK * 2) / 4096;
  constexpr int BI = (BN * BK * 2) / 4096;
  __shared__ bf16 Ash[BM * BK];
  __shared__ bf16 Asl[BM * BK];
  __shared__ bf16 Bsh[BN * BK];
  __shared__ bf16 Bsl[BN * BK];

  const int z = blockIdx.z;
  A += (long long)z * sAz;
  B += (long long)z * sBz;
  const int bm0 = blockIdx.x * BM;
  const int bn0 = blockIdx.y * BN;
  const int t = threadIdx.x;
  const int wave = t >> 6, lane = t & 63;
  const int wr = wave / WAVES_N, wc = wave % WAVES_N;
  const int sr = t >> 2, sc = t & 3;
  const int frow = lane & 15, fk = (lane >> 4) * 8;

  f32x4 acc[MF][NF] = {};

  for (int k0 = 0; k0 < K; k0 += BK) {
#pragma unroll
    for (int qi = 0; qi < AI; ++qi) {
      const long long ro = (long long)(bm0 + qi * 64 + sr) * lda + (k0 + sc * 8);
      __builtin_amdgcn_global_load_lds(
          (const __attribute__((address_space(1))) void*)(A + ro),
          (__attribute__((address_space(3))) void*)(Ash + qi * 2048 + wave * 512), 16, 0, 0);
      __builtin_amdgcn_global_load_lds(
          (const __attribute__((address_space(1))) void*)(A + ro + K),
          (__attribute__((address_space(3))) void*)(Asl + qi * 2048 + wave * 512), 16, 0, 0);
    }
#pragma unroll
    for (int qi = 0; qi < BI; ++qi) {
      const long long ro = (long long)(bn0 + qi * 64 + sr) * ldb + (k0 + sc * 8);
      __builtin_amdgcn_global_load_lds(
          (const __attribute__((address_space(1))) void*)(B + ro),
          (__attribute__((address_space(3))) void*)(Bsh + qi * 2048 + wave * 512), 16, 0, 0);
      __builtin_amdgcn_global_load_lds(
          (const __attribute__((address_space(1))) void*)(B + ro + K),
          (__attribute__((address_space(3))) void*)(Bsl + qi * 2048 + wave * 512), 16, 0, 0);
    }
    __syncthreads();
    bf16x8 afh[MF], afl[MF], bfh[NF], bfl[NF];
#pragma unroll
    for (int m = 0; m < MF; m++) {
      afh[m] = *(const bf16x8*)(Ash + (wr * WM + m * 16 + frow) * BK + fk);
      afl[m] = *(const bf16x8*)(Asl + (wr * WM + m * 16 + frow) * BK + fk);
    }
#pragma unroll
    for (int n = 0; n < NF; n++) {
      bfh[n] = *(const bf16x8*)(Bsh + (wc * WN + n * 16 + frow) * BK + fk);
      bfl[n] = *(const bf16x8*)(Bsl + (wc * WN + n * 16 + frow) * BK + fk);
    }
#pragma unroll
    for (int m = 0; m < MF; m++)
#pragma unroll
      for (int n = 0; n < NF; n++) {
        acc[m][n] = __builtin_amdgcn_mfma_f32_16x16x32_bf16(afh[m], bfh[n], acc[m][n], 0, 0, 0);
        acc[m][n] = __builtin_amdgcn_mfma_f32_16x16x32_bf16(afl[m], bfh[n], acc[m][n], 0, 0, 0);
        acc[m][n] = __builtin_amdgcn_mfma_f32_16x16x32_bf16(afh[m], bfl[n], acc[m][n], 0, 0, 0);
      }
    __syncthreads();
  }

  // C/D layout: col=lane&15, row=(lane>>4)*4+reg
#pragma unroll
  for (int m = 0; m < MF; m++) {
#pragma unroll
    for (int n = 0; n < NF; n++) {
      const int row0 = bm0 + wr * WM + m * 16 + (lane >> 4) * 4;
      const int col = bn0 + wc * WN + n * 16 + (lane & 15);
#pragma unroll
      for (int r = 0; r < 4; r++) {
        const float v = acc[m][n][r];
        const long long i = row0 + r;
        if (EPI == EPI_F32) {
          (((float*)Cv) + z * sCz)[i * ldc + col] = v;
        } else if (EPI == EPI_DOTS) {
          float o = -1e30f;
          if (col < NJ) o = v + bias[(col - (int)i + 2047) * 8 + (kh0 + z)];
          (((float*)Cv) + z * sCz)[i * ldc + col] = o;
        } else if (EPI == EPI_SPLIT) {
          bf16* base = ((bf16*)Cv) + z * sCz;
          const long long ih = i * (long long)(2 * ldc) + col;
          bf16 h = (bf16)v;
          base[ih] = h;
          base[ih + ldc] = (bf16)(v - (float)h);
        } else if (EPI == EPI_GELUSPLIT) {
          float u = v + bias[col];
          float gl = 0.5f * u * (1.0f + erff(u * 0.7071067811865476f));
          const long long ih = i * (long long)(2 * ldc) + col;
          bf16 h = (bf16)gl;
          ((bf16*)Cv)[ih] = h;
          ((bf16*)Cv)[ih + ldc] = (bf16)(gl - (float)h);
        } else {  // EPI_RESID
          float* xp = ((float*)Cv) + i * ldc + col;
          *xp = *xp + v + bias[col];
        }
      }
    }
  }
}

// ---------------------------------------------------------------------------
// LayerNorm -> split bf16 (hi | lo), row stride 1024
// ---------------------------------------------------------------------------
__global__ __launch_bounds__(256)
void ln_kernel(const float* __restrict__ x, const float* __restrict__ g,
               const float* __restrict__ b, bf16* __restrict__ out)
{
  const int row = blockIdx.x * 4 + (threadIdx.x >> 6);
  const int lane = threadIdx.x & 63;
  const float* xr = x + (long long)row * NDIM;
  float4 a0 = ((const float4*)xr)[lane];
  float4 a1 = ((const float4*)xr)[lane + 64];
  float s = a0.x + a0.y + a0.z + a0.w + a1.x + a1.y + a1.z + a1.w;
  float ss = a0.x * a0.x + a0.y * a0.y + a0.z * a0.z + a0.w * a0.w
           + a1.x * a1.x + a1.y * a1.y + a1.z * a1.z + a1.w * a1.w;
#pragma unroll
  for (int d = 1; d < 64; d <<= 1) {
    s += __shfl_xor(s, d, 64);
    ss += __shfl_xor(ss, d, 64);
  }
  const float mean = s * (1.0f / NDIM);
  const float var = ss * (1.0f / NDIM) - mean * mean;
  const float rs = rsqrtf(var + 1e-5f);
  float4 g0 = ((const float4*)g)[lane], g1 = ((const float4*)g)[lane + 64];
  float4 b0 = ((const float4*)b)[lane], b1 = ((const float4*)b)[lane + 64];
  bf16* orow = out + (long long)row * (2 * NDIM);
  float y[8] = {
    (a0.x - mean) * rs * g0.x + b0.x, (a0.y - mean) * rs * g0.y + b0.y,
    (a0.z - mean) * rs * g0.z + b0.z, (a0.w - mean) * rs * g0.w + b0.w,
    (a1.x - mean) * rs * g1.x + b1.x, (a1.y - mean) * rs * g1.y + b1.y,
    (a1.z - mean) * rs * g1.z + b1.z, (a1.w - mean) * rs * g1.w + b1.w };
  bf16x4 h0, h1, l0, l1;
#pragma unroll
  for (int j = 0; j < 4; j++) {
    bf16 h = (bf16)y[j];      h0[j] = h;  l0[j] = (bf16)(y[j] - (float)h);
    bf16 h2 = (bf16)y[4 + j]; h1[j] = h2; l1[j] = (bf16)(y[4 + j] - (float)h2);
  }
  *(bf16x4*)(orow + lane * 4) = h0;
  *(bf16x4*)(orow + 256 + lane * 4) = h1;
  *(bf16x4*)(orow + 512 + lane * 4) = l0;
  *(bf16x4*)(orow + 768 + lane * 4) = l1;
}

// ---------------------------------------------------------------------------
// top-8 threshold + softmax, IN-PLACE: reads fp32 row, writes split-bf16 row
// over the same bytes (NJP f32 == 2*NJP bf16). One wave per row.
// ---------------------------------------------------------------------------
__global__ __launch_bounds__(256)
void topk_softmax(float* dots)
{
  const int row = blockIdx.x * 4 + (threadIdx.x >> 6);
  const int lane = threadIdx.x & 63;
  float* dr = dots + (long long)row * NJP;
  float v[34];
  float t8[8];
#pragma unroll
  for (int i = 0; i < 8; i++) t8[i] = -3.0e38f;
#pragma unroll
  for (int t = 0; t < 34; t++) {
    float xv = dr[lane + 64 * t];
    v[t] = xv;
    if (xv > t8[7]) {
      t8[7] = xv;
#pragma unroll
      for (int i = 6; i >= 0; i--) {
        if (t8[i + 1] > t8[i]) { float tmp = t8[i]; t8[i] = t8[i + 1]; t8[i + 1] = tmp; }
      }
    }
  }
#pragma unroll
  for (int d = 1; d < 64; d <<= 1) {
    float o[8], m[8];
#pragma unroll
    for (int i = 0; i < 8; i++) o[i] = __shfl_xor(t8[i], d, 64);
#pragma unroll
    for (int i = 0; i < 8; i++) m[i] = fmaxf(t8[i], o[7 - i]);
#define CX(a, b) { float hi = fmaxf(m[a], m[b]); float lo = fminf(m[a], m[b]); m[a] = hi; m[b] = lo; }
    CX(0, 4) CX(1, 5) CX(2, 6) CX(3, 7)
    CX(0, 2) CX(1, 3) CX(4, 6) CX(5, 7)
    CX(0, 1) CX(2, 3) CX(4, 5) CX(6, 7)
#undef CX
#pragma unroll
    for (int i = 0; i < 8; i++) t8[i] = m[i];
  }
  const float thr = t8[7];
  const float mx = t8[0];
  float s = 0.f;
#pragma unroll
  for (int t = 0; t < 34; t++) {
    float p = (v[t] >= thr) ? expf(v[t] - mx) : 0.f;
    v[t] = p;
    s += p;
  }
#pragma unroll
  for (int d = 1; d < 64; d <<= 1) s += __shfl_xor(s, d, 64);
  const float inv = 1.0f / s;
  bf16* ar = ((bf16*)dots) + (long long)row * (2 * NJP);
#pragma unroll
  for (int t = 0; t < 34; t++) {
    float w = v[t] * inv;
    bf16 h = (bf16)w;
    ar[lane + 64 * t] = h;
    ar[NJP + lane + 64 * t] = (bf16)(w - (float)h);
  }
}

// ---------------------------------------------------------------------------
// Qp (one batch): Qp[k][i][.] = split( q_b[i,c] * pp[c>>6, k] * 0.125 )
// ---------------------------------------------------------------------------
__global__ __launch_bounds__(256)
void build_qp(const float* __restrict__ q_b, const float* __restrict__ pp,
              bf16* __restrict__ Qp)
{
  const long long e = ((long long)blockIdx.x * 256 + threadIdx.x) * 4;
  const int c = (int)(e & 511);
  const int i = (int)((e >> 9) & 2047);
  const int kh = (int)((e >> 20) & 7);
  const float4 qq = *(const float4*)(q_b + ((long long)i * NDIM + c));
  const float f = pp[(c >> 6) * 8 + kh] * 0.125f;
  float y[4] = { qq.x * f, qq.y * f, qq.z * f, qq.w * f };
  bf16x4 hv, lv;
#pragma unroll
  for (int j = 0; j < 4; j++) { bf16 h = (bf16)y[j]; hv[j] = h; lv[j] = (bf16)(y[j] - (float)h); }
  const long long ro = ((long long)kh * NSEQ + i) * (2 * NDIM) + c;
  *(bf16x4*)(Qp + ro) = hv;
  *(bf16x4*)(Qp + ro + NDIM) = lv;
}

// ---------------------------------------------------------------------------
// Kmat[b][j][.] (split), VT[b][c][.] (split); mem slots + zero pad
// ---------------------------------------------------------------------------
__global__ __launch_bounds__(256)
void build_kv(const float* __restrict__ kv, const float* __restrict__ mem_k_l,
              const float* __restrict__ mem_v_l, bf16* __restrict__ Kmat,
              bf16* __restrict__ VT)
{
  const long long idx = (long long)blockIdx.x * 256 + threadIdx.x;  // [b][j][c]
  const int c = (int)(idx & 511);
  const int j = (int)((idx >> 9) % NJP);
  const int bb = (int)(idx / ((long long)NJP * NDIM));
  const int h = c >> 6, d = c & 63;
  float kval, vval;
  if (j < NMEM) {
    kval = mem_k_l[(h * NMEM + j) * DHEAD + d];
    vval = mem_v_l[(h * NMEM + j) * DHEAD + d];
  } else if (j < NJ) {
    const float* rowp = kv + (long long)(bb * NSEQ + (j - NMEM)) * (2 * NDIM);
    kval = rowp[c];
    vval = rowp[NDIM + c];
  } else {
    kval = 0.f; vval = 0.f;
  }
  bf16 kh_ = (bf16)kval, vh = (bf16)vval;
  const long long kro = ((long long)bb * NJP + j) * (2 * NDIM) + c;
  Kmat[kro] = kh_;
  Kmat[kro + NDIM] = (bf16)(kval - (float)kh_);
  const long long vro = ((long long)bb * NDIM + c) * (2 * NJP) + j;
  VT[vro] = vh;
  VT[vro + NJP] = (bf16)(vval - (float)vh);
}

// ---------------------------------------------------------------------------
// fp32 weight (R x C row-major) -> split-transposed bf16 (C x 2R)
// ---------------------------------------------------------------------------
__global__ __launch_bounds__(256)
void transpose_split(const float* __restrict__ in, bf16* __restrict__ out,
                     int R, int C)
{
  const long long idx = (long long)blockIdx.x * 256 + threadIdx.x;
  if (idx >= (long long)R * C) return;
  const int r = (int)(idx / C);
  const int c = (int)(idx % C);
  float v = in[idx];
  bf16 h = (bf16)v;
  out[(long long)c * (2 * R) + r] = h;
  out[(long long)c * (2 * R) + R + r] = (bf16)(v - (float)h);
}

// ---------------------------------------------------------------------------
// T5 bias table. Bucket boundaries (n=16,32,64,128) are exact integer cliffs:
// log2 of a power of two is exact, so (int) truncation matches numpy.
// ---------------------------------------------------------------------------
__global__ __launch_bounds__(256)
void build_bias(const float* __restrict__ rel_emb, float* __restrict__ table)
{
  const int idx = blockIdx.x * 256 + threadIdx.x;
  if (idx >= 4111 * 8) return;
  const int h = idx & 7;
  const int rel = (idx >> 3) - 2047;  // rel = j - i
  const int n = -rel;
  const int ret = (n < 0) ? 16 : 0;
  const int na = n < 0 ? -n : n;
  int bucket;
  if (na < 8) {
    bucket = ret + na;
  } else {
    // log(n/8)/log(16)*8 == log2(n/8)*2
    int vl = 8 + (int)(log2((double)na * 0.125) * 2.0);
    vl = vl < 15 ? vl : 15;
    bucket = ret + vl;
  }
  table[idx] = rel_emb[bucket * 8 + h];
}

// ---------------------------------------------------------------------------
extern "C" void kernel_launch(void* const* d_in, const int* in_sizes, int n_in,
                              void* d_out, int out_size, void* d_ws, size_t ws_size,
                              hipStream_t stream)
{
  const float* x_in    = (const float*)d_in[0];
  const float* ln1_g   = (const float*)d_in[1];
  const float* ln1_b   = (const float*)d_in[2];
  const float* Wq      = (const float*)d_in[3];
  const float* Wkv     = (const float*)d_in[4];
  const float* Wo      = (const float*)d_in[5];
  const float* bo      = (const float*)d_in[6];
  const float* pre_proj= (const float*)d_in[7];
  const float* mem_k   = (const float*)d_in[8];
  const float* mem_v   = (const float*)d_in[9];
  const float* ln2_g   = (const float*)d_in[10];
  const float* ln2_b   = (const float*)d_in[11];
  const float* W1      = (const float*)d_in[12];
  const float* b1      = (const float*)d_in[13];
  const float* W2      = (const float*)d_in[14];
  const float* b2      = (const float*)d_in[15];
  const float* rel_emb = (const float*)d_in[16];

  char* p = (char*)d_ws;
  auto alloc = [&](size_t bytes) -> char* {
    char* r = p;
    p += (bytes + 255) & ~(size_t)255;
    return r;
  };

  // Fixed buffers (~119 MB total), with phase-disjoint aliasing:
  float* x  = (float*)alloc((size_t)NROWS * NDIM * 4);            // 8.4 MB
  bf16*  hs = (bf16*) alloc((size_t)NROWS * 2 * NDIM * 2);        // 8.4 MB
  float* q  = (float*)alloc((size_t)NROWS * NDIM * 4);            // 8.4 MB
  char*  R2 = alloc((size_t)NROWS * 2 * NDIM * 4);                // 16.8 MB: kv | obufs
  float* kv    = (float*)R2;
  bf16*  obufs = (bf16*)R2;
  char*  R1 = alloc((size_t)NHEADS * NSEQ * 2 * NDIM * 2);        // 33.6 MB: Qp | tbufs
  bf16*  Qp    = (bf16*)R1;
  bf16*  tbufs = (bf16*)R1;
  bf16*  Kmat = (bf16*)alloc((size_t)NB * NJP * 2 * NDIM * 2);    // 8.9 MB
  bf16*  VT   = (bf16*)alloc((size_t)NB * NDIM * 2 * NJP * 2);    // 8.9 MB
  bf16*  WqT  = (bf16*)alloc((size_t)2 * NDIM * 2 * NDIM * 2);
  bf16*  WkvT = (bf16*)alloc((size_t)2 * 2 * NDIM * 2 * NDIM * 2);
  bf16*  WoT  = (bf16*)alloc((size_t)2 * NDIM * 2 * NDIM * 2);
  bf16*  W1T  = (bf16*)alloc((size_t)2 * NFF * 2 * NDIM * 2);
  bf16*  W2T  = (bf16*)alloc((size_t)2 * NDIM * 2 * NFF * 2);
  float* table= (float*)alloc((size_t)4111 * 8 * 4);

  // dots (attn aliases dots in-place): chunk heads at a time
  size_t fixed_end = (size_t)(p - (char*)d_ws);
  const size_t per_chunk = (((size_t)NSEQ * NJP * 4) + 255) & ~(size_t)255;
  int chunk = 8;
  while (chunk > 1 && fixed_end + (size_t)chunk * per_chunk > ws_size) chunk >>= 1;
  float* dots = (float*)alloc((size_t)chunk * per_chunk);

  // ---- prep ----
  hipMemcpyAsync(x, x_in, (size_t)NROWS * NDIM * 4, hipMemcpyDeviceToDevice, stream);
  build_bias<<<(4111 * 8 + 255) / 256, 256, 0, stream>>>(rel_emb, table);
  for (int l = 0; l < 2; l++) {
    transpose_split<<<(NDIM * NDIM + 255) / 256, 256, 0, stream>>>(
        Wq + (size_t)l * NDIM * NDIM, WqT + (size_t)l * NDIM * 2 * NDIM, NDIM, NDIM);
    transpose_split<<<(2 * NDIM * NDIM + 255) / 256, 256, 0, stream>>>(
        Wkv + (size_t)l * NDIM * 2 * NDIM, WkvT + (size_t)l * 2 * NDIM * 2 * NDIM, NDIM, 2 * NDIM);
    transpose_split<<<(NDIM * NDIM + 255) / 256, 256, 0, stream>>>(
        Wo + (size_t)l * NDIM * NDIM, WoT + (size_t)l * NDIM * 2 * NDIM, NDIM, NDIM);
    transpose_split<<<(NDIM * NFF + 255) / 256, 256, 0, stream>>>(
        W1 + (size_t)l * NDIM * NFF, W1T + (size_t)l * NFF * 2 * NDIM, NDIM, NFF);
    transpose_split<<<(NFF * NDIM + 255) / 256, 256, 0, stream>>>(
        W2 + (size_t)l * NFF * NDIM, W2T + (size_t)l * NDIM * 2 * NFF, NFF, NDIM);
  }

  // ---- layers ----
  for (int l = 0; l < 2; l++) {
    const bf16* WqT_l  = WqT + (size_t)l * NDIM * 2 * NDIM;
    const bf16* WkvT_l = WkvT + (size_t)l * 2 * NDIM * 2 * NDIM;
    const bf16* WoT_l  = WoT + (size_t)l * NDIM * 2 * NDIM;
    const bf16* W1T_l  = W1T + (size_t)l * NFF * 2 * NDIM;
    const bf16* W2T_l  = W2T + (size_t)l * NDIM * 2 * NFF;

    ln_kernel<<<NROWS / 4, 256, 0, stream>>>(x, ln1_g + l * NDIM, ln1_b + l * NDIM, hs);
    gemm_split<128, 128, 2, 2, EPI_F32><<<dim3(NROWS / 128, NDIM / 128, 1), 256, 0, stream>>>(
        hs, WqT_l, q, nullptr, NDIM, 2 * NDIM, 2 * NDIM, NDIM, 0, 0, 0, 0);
    gemm_split<128, 128, 2, 2, EPI_F32><<<dim3(NROWS / 128, 2 * NDIM / 128, 1), 256, 0, stream>>>(
        hs, WkvT_l, kv, nullptr, NDIM, 2 * NDIM, 2 * NDIM, 2 * NDIM, 0, 0, 0, 0);
    build_kv<<<(int)(((long long)NB * NJP * NDIM) / 256), 256, 0, stream>>>(
        kv, mem_k + (size_t)l * NHEADS * NMEM * DHEAD,
        mem_v + (size_t)l * NHEADS * NMEM * DHEAD, Kmat, VT);

    for (int b = 0; b < NB; b++) {
      build_qp<<<(int)(((long long)NHEADS * NSEQ * NDIM / 4) / 256), 256, 0, stream>>>(
          q + (size_t)b * NSEQ * NDIM, pre_proj + l * 64, Qp);
      for (int kh0 = 0; kh0 < NHEADS; kh0 += chunk) {
        gemm_split<128, 128, 2, 2, EPI_DOTS><<<dim3(NSEQ / 128, NJP / 128, chunk), 256, 0, stream>>>(
            Qp + (size_t)kh0 * NSEQ * 2 * NDIM,
            Kmat + (size_t)b * NJP * 2 * NDIM,
            dots, table, NDIM, 2 * NDIM, 2 * NDIM, NJP,
            (long long)NSEQ * 2 * NDIM, 0, (long long)NSEQ * NJP, kh0);
        topk_softmax<<<(chunk * NSEQ) / 4, 256, 0, stream>>>(dots);
        gemm_split<128, 64, 4, 1, EPI_SPLIT><<<dim3(NSEQ / 128, 1, chunk), 256, 0, stream>>>(
            (const bf16*)dots,
            VT + (size_t)b * NDIM * 2 * NJP + (size_t)kh0 * DHEAD * 2 * NJP,
            obufs + (size_t)b * NSEQ * 2 * NDIM + (size_t)kh0 * DHEAD,
            nullptr, NJP, 2 * NJP, 2 * NJP, NDIM,
            (long long)NSEQ * 2 * NJP, (long long)DHEAD * 2 * NJP, DHEAD, 0);
      }
    }

    gemm_split<128, 128, 2, 2, EPI_RESID><<<dim3(NROWS / 128, NDIM / 128, 1), 256, 0, stream>>>(
        obufs, WoT_l, x, bo + l * NDIM, NDIM, 2 * NDIM, 2 * NDIM, NDIM, 0, 0, 0, 0);

    ln_kernel<<<NROWS / 4, 256, 0, stream>>>(x, ln2_g + l * NDIM, ln2_b + l * NDIM, hs);
    gemm_split<128, 128, 2, 2, EPI_GELUSPLIT><<<dim3(NROWS / 128, NFF / 128, 1), 256, 0, stream>>>(
        hs, W1T_l, tbufs, b1 + l * NFF, NDIM, 2 * NDIM, 2 * NDIM, NFF, 0, 0, 0, 0);
    gemm_split<128, 128, 2, 2, EPI_RESID><<<dim3(NROWS / 128, NDIM / 128, 1), 256, 0, stream>>>(
        tbufs, W2T_l, x, b2 + l * NDIM, NFF, 2 * NFF, 2 * NFF, NDIM, 0, 0, 0, 0);
  }

  hipMemcpyAsync(d_out, x, (size_t)out_size * 4, hipMemcpyDeviceToDevice, stream);
}

// Round 4
// 1222.131 us; speedup vs baseline: 1.4819x; 1.4819x over previous
//
#include <hip/hip_runtime.h>
#include <cmath>

typedef __bf16 bf16;
typedef __attribute__((ext_vector_type(8))) __bf16 bf16x8;
typedef __attribute__((ext_vector_type(4))) __bf16 bf16x4;
typedef __attribute__((ext_vector_type(4))) float f32x4;

#define NB 2
#define NSEQ 2048
#define NDIM 512
#define NHEADS 8
#define DHEAD 64
#define NMEM 16
#define NJ 2064
#define NJP 2176        // 17*128
#define NFF 2048
#define NROWS (NB*NSEQ) // 4096
#define PLANE ((long long)NSEQ * NJP)

enum { EPI_F32 = 0, EPI_SPLIT = 1, EPI_GELUSPLIT = 2, EPI_RESID = 3 };

// ---------------------------------------------------------------------------
// Split-precision GEMM: fp32 operands stored as bf16 (hi,lo). hi at col c,
// lo at col c+loA (A) / c+loB (B). C = Ah*Bh + Al*Bh + Ah*Bl, fp32 accum.
// ---------------------------------------------------------------------------
template<int BM, int BN, int WAVES_M, int WAVES_N, int EPI>
__global__ __launch_bounds__(256)
void gemm_split(const bf16* __restrict__ A, const bf16* __restrict__ B,
                void* __restrict__ Cv, const float* __restrict__ bias,
                int K, int lda, int ldb, int ldc, int loA, int loB,
                long long sAz, long long sBz, long long sCz, float scale)
{
  constexpr int BK = 32;
  constexpr int WM = BM / WAVES_M;
  constexpr int WN = BN / WAVES_N;
  constexpr int MF = WM / 16;
  constexpr int NF = WN / 16;
  constexpr int AI = (BM * BK * 2) / 4096;
  constexpr int BI = (BN * BK * 2) / 4096;
  __shared__ bf16 Ash[BM * BK];
  __shared__ bf16 Asl[BM * BK];
  __shared__ bf16 Bsh[BN * BK];
  __shared__ bf16 Bsl[BN * BK];

  const int z = blockIdx.z;
  A += (long long)z * sAz;
  B += (long long)z * sBz;
  const int bm0 = blockIdx.x * BM;
  const int bn0 = blockIdx.y * BN;
  const int t = threadIdx.x;
  const int wave = t >> 6, lane = t & 63;
  const int wr = wave / WAVES_N, wc = wave % WAVES_N;
  const int sr = t >> 2, sc = t & 3;
  const int frow = lane & 15, fk = (lane >> 4) * 8;

  f32x4 acc[MF][NF] = {};

  for (int k0 = 0; k0 < K; k0 += BK) {
#pragma unroll
    for (int qi = 0; qi < AI; ++qi) {
      const long long ro = (long long)(bm0 + qi * 64 + sr) * lda + (k0 + sc * 8);
      __builtin_amdgcn_global_load_lds(
          (const __attribute__((address_space(1))) void*)(A + ro),
          (__attribute__((address_space(3))) void*)(Ash + qi * 2048 + wave * 512), 16, 0, 0);
      __builtin_amdgcn_global_load_lds(
          (const __attribute__((address_space(1))) void*)(A + ro + loA),
          (__attribute__((address_space(3))) void*)(Asl + qi * 2048 + wave * 512), 16, 0, 0);
    }
#pragma unroll
    for (int qi = 0; qi < BI; ++qi) {
      const long long ro = (long long)(bn0 + qi * 64 + sr) * ldb + (k0 + sc * 8);
      __builtin_amdgcn_global_load_lds(
          (const __attribute__((address_space(1))) void*)(B + ro),
          (__attribute__((address_space(3))) void*)(Bsh + qi * 2048 + wave * 512), 16, 0, 0);
      __builtin_amdgcn_global_load_lds(
          (const __attribute__((address_space(1))) void*)(B + ro + loB),
          (__attribute__((address_space(3))) void*)(Bsl + qi * 2048 + wave * 512), 16, 0, 0);
    }
    __syncthreads();
    bf16x8 afh[MF], afl[MF], bfh[NF], bfl[NF];
#pragma unroll
    for (int m = 0; m < MF; m++) {
      afh[m] = *(const bf16x8*)(Ash + (wr * WM + m * 16 + frow) * BK + fk);
      afl[m] = *(const bf16x8*)(Asl + (wr * WM + m * 16 + frow) * BK + fk);
    }
#pragma unroll
    for (int n = 0; n < NF; n++) {
      bfh[n] = *(const bf16x8*)(Bsh + (wc * WN + n * 16 + frow) * BK + fk);
      bfl[n] = *(const bf16x8*)(Bsl + (wc * WN + n * 16 + frow) * BK + fk);
    }
#pragma unroll
    for (int m = 0; m < MF; m++)
#pragma unroll
      for (int n = 0; n < NF; n++) {
        acc[m][n] = __builtin_amdgcn_mfma_f32_16x16x32_bf16(afh[m], bfh[n], acc[m][n], 0, 0, 0);
        acc[m][n] = __builtin_amdgcn_mfma_f32_16x16x32_bf16(afl[m], bfh[n], acc[m][n], 0, 0, 0);
        acc[m][n] = __builtin_amdgcn_mfma_f32_16x16x32_bf16(afh[m], bfl[n], acc[m][n], 0, 0, 0);
      }
    __syncthreads();
  }

  // C/D layout: col=lane&15, row=(lane>>4)*4+reg
#pragma unroll
  for (int m = 0; m < MF; m++) {
#pragma unroll
    for (int n = 0; n < NF; n++) {
      const int row0 = bm0 + wr * WM + m * 16 + (lane >> 4) * 4;
      const int col = bn0 + wc * WN + n * 16 + (lane & 15);
#pragma unroll
      for (int r = 0; r < 4; r++) {
        const float v = acc[m][n][r] * scale;
        const long long i = row0 + r;
        if (EPI == EPI_F32) {
          (((float*)Cv) + z * sCz)[i * ldc + col] = v;
        } else if (EPI == EPI_SPLIT) {
          bf16* base = ((bf16*)Cv) + z * sCz;
          const long long ih = i * (long long)(2 * ldc) + col;
          bf16 h = (bf16)v;
          base[ih] = h;
          base[ih + ldc] = (bf16)(v - (float)h);
        } else if (EPI == EPI_GELUSPLIT) {
          float u = v + bias[col];
          float gl = 0.5f * u * (1.0f + erff(u * 0.7071067811865476f));
          const long long ih = i * (long long)(2 * ldc) + col;
          bf16 h = (bf16)gl;
          ((bf16*)Cv)[ih] = h;
          ((bf16*)Cv)[ih + ldc] = (bf16)(gl - (float)h);
        } else {  // EPI_RESID
          float* xp = ((float*)Cv) + i * ldc + col;
          *xp = *xp + v + bias[col];
        }
      }
    }
  }
}

// ---------------------------------------------------------------------------
// LayerNorm -> split bf16 (hi | lo), row stride 1024
// ---------------------------------------------------------------------------
__global__ __launch_bounds__(256)
void ln_kernel(const float* __restrict__ x, const float* __restrict__ g,
               const float* __restrict__ b, bf16* __restrict__ out)
{
  const int row = blockIdx.x * 4 + (threadIdx.x >> 6);
  const int lane = threadIdx.x & 63;
  const float* xr = x + (long long)row * NDIM;
  float4 a0 = ((const float4*)xr)[lane];
  float4 a1 = ((const float4*)xr)[lane + 64];
  float s = a0.x + a0.y + a0.z + a0.w + a1.x + a1.y + a1.z + a1.w;
  float ss = a0.x * a0.x + a0.y * a0.y + a0.z * a0.z + a0.w * a0.w
           + a1.x * a1.x + a1.y * a1.y + a1.z * a1.z + a1.w * a1.w;
#pragma unroll
  for (int d = 1; d < 64; d <<= 1) {
    s += __shfl_xor(s, d, 64);
    ss += __shfl_xor(ss, d, 64);
  }
  const float mean = s * (1.0f / NDIM);
  const float var = ss * (1.0f / NDIM) - mean * mean;
  const float rs = rsqrtf(var + 1e-5f);
  float4 g0 = ((const float4*)g)[lane], g1 = ((const float4*)g)[lane + 64];
  float4 b0 = ((const float4*)b)[lane], b1 = ((const float4*)b)[lane + 64];
  bf16* orow = out + (long long)row * (2 * NDIM);
  float y[8] = {
    (a0.x - mean) * rs * g0.x + b0.x, (a0.y - mean) * rs * g0.y + b0.y,
    (a0.z - mean) * rs * g0.z + b0.z, (a0.w - mean) * rs * g0.w + b0.w,
    (a1.x - mean) * rs * g1.x + b1.x, (a1.y - mean) * rs * g1.y + b1.y,
    (a1.z - mean) * rs * g1.z + b1.z, (a1.w - mean) * rs * g1.w + b1.w };
  bf16x4 h0, h1, l0, l1;
#pragma unroll
  for (int j = 0; j < 4; j++) {
    bf16 h = (bf16)y[j];      h0[j] = h;  l0[j] = (bf16)(y[j] - (float)h);
    bf16 h2 = (bf16)y[4 + j]; h1[j] = h2; l1[j] = (bf16)(y[4 + j] - (float)h2);
  }
  *(bf16x4*)(orow + lane * 4) = h0;
  *(bf16x4*)(orow + 256 + lane * 4) = h1;
  *(bf16x4*)(orow + 512 + lane * 4) = l0;
  *(bf16x4*)(orow + 768 + lane * 4) = l1;
}

// ---------------------------------------------------------------------------
// Ks[b][j][c]=hi, [c+512]=lo from kv k-part + mem_k; zero pad rows
// ---------------------------------------------------------------------------
__global__ __launch_bounds__(256)
void build_ks(const float* __restrict__ kv, const float* __restrict__ mem_k_l,
              bf16* __restrict__ Ks)
{
  const long long idx = (long long)blockIdx.x * 256 + threadIdx.x;  // [b][j][c]
  const int c = (int)(idx & 511);
  const int j = (int)((idx >> 9) % NJP);
  const int bb = (int)(idx / ((long long)NJP * NDIM));
  const int h = c >> 6, d = c & 63;
  float kval;
  if (j < NMEM) kval = mem_k_l[(h * NMEM + j) * DHEAD + d];
  else if (j < NJ) kval = kv[(long long)(bb * NSEQ + (j - NMEM)) * (2 * NDIM) + c];
  else kval = 0.f;
  bf16 hv = (bf16)kval;
  const long long ro = ((long long)bb * NJP + j) * (2 * NDIM) + c;
  Ks[ro] = hv;
  Ks[ro + NDIM] = (bf16)(kval - (float)hv);
}

// ---------------------------------------------------------------------------
// In-place talking-heads mix + bias + pad over the 8 S planes (one batch).
// mixed[k][i][j] = sum_h pp[h*8+k] * S[h][i][j] + table[(j-i+2047)*8+k]
// Each thread owns 4 consecutive j at one i across all planes -> race-free.
// ---------------------------------------------------------------------------
__global__ __launch_bounds__(256)
void mix_bias(float* S, const float* __restrict__ pp,
              const float* __restrict__ table)
{
  const long long idx = (long long)blockIdx.x * 256 + threadIdx.x;  // < 2048*544
  const int i = (int)(idx / (NJP / 4));
  const int j = (int)(idx % (NJP / 4)) * 4;
  float4 s[8];
#pragma unroll
  for (int h = 0; h < 8; h++)
    s[h] = *(const float4*)(S + h * PLANE + (long long)i * NJP + j);
  float4 o[8];
#pragma unroll
  for (int e = 0; e < 4; e++) {
    const int jj = j + e;
    float m[8];
    if (jj < NJ) {
      const float* tb = table + (jj - i + 2047) * 8;
#pragma unroll
      for (int k = 0; k < 8; k++) m[k] = tb[k];
#pragma unroll
      for (int h = 0; h < 8; h++) {
        const float sv = ((const float*)&s[h])[e];
#pragma unroll
        for (int k = 0; k < 8; k++) m[k] = fmaf(sv, pp[h * 8 + k], m[k]);
      }
    } else {
#pragma unroll
      for (int k = 0; k < 8; k++) m[k] = -1e30f;
    }
#pragma unroll
    for (int k = 0; k < 8; k++) ((float*)&o[k])[e] = m[k];
  }
#pragma unroll
  for (int k = 0; k < 8; k++)
    *(float4*)(S + k * PLANE + (long long)i * NJP + j) = o[k];
}

// ---------------------------------------------------------------------------
// Fused top-8 + softmax + sparse PV gather. One wave per (head k, row i).
// Reads mixed scores; tracks (val,idx) top-8 via butterfly bitonic merge;
// gathers 8 V rows from fp32 kv/mem_v; writes split-bf16 attn output.
// ---------------------------------------------------------------------------
__global__ __launch_bounds__(256)
void topk_gather(const float* __restrict__ S, const float* __restrict__ kv,
                 const float* __restrict__ mem_v_l, bf16* __restrict__ obufs,
                 int b)
{
  const int row = blockIdx.x * 4 + (threadIdx.x >> 6);  // 0..16383
  const int k = row >> 11;
  const int i = row & 2047;
  const int lane = threadIdx.x & 63;
  const float* dr = S + (long long)k * PLANE + (long long)i * NJP;

  float t8[8]; int i8_[8];
#pragma unroll
  for (int m = 0; m < 8; m++) { t8[m] = -3.0e38f; i8_[m] = 0; }
#pragma unroll
  for (int t = 0; t < 34; t++) {
    const float xv = dr[lane + 64 * t];
    if (xv > t8[7]) {
      t8[7] = xv; i8_[7] = lane + 64 * t;
#pragma unroll
      for (int m = 6; m >= 0; m--) {
        if (t8[m + 1] > t8[m]) {
          float tv = t8[m]; t8[m] = t8[m + 1]; t8[m + 1] = tv;
          int ti = i8_[m]; i8_[m] = i8_[m + 1]; i8_[m + 1] = ti;
        }
      }
    }
  }
#pragma unroll
  for (int d = 1; d < 64; d <<= 1) {
    float ov[8]; int oi[8];
#pragma unroll
    for (int m = 0; m < 8; m++) {
      ov[m] = __shfl_xor(t8[m], d, 64);
      oi[m] = __shfl_xor(i8_[m], d, 64);
    }
    float nv[8]; int ni[8];
#pragma unroll
    for (int m = 0; m < 8; m++) {
      const bool c = t8[m] >= ov[7 - m];
      nv[m] = c ? t8[m] : ov[7 - m];
      ni[m] = c ? i8_[m] : oi[7 - m];
    }
#define CXI(a, bq) { const bool c = nv[a] >= nv[bq]; \
    float va = c ? nv[a] : nv[bq], vb = c ? nv[bq] : nv[a]; \
    int ia = c ? ni[a] : ni[bq], ib = c ? ni[bq] : ni[a]; \
    nv[a] = va; nv[bq] = vb; ni[a] = ia; ni[bq] = ib; }
    CXI(0, 4) CXI(1, 5) CXI(2, 6) CXI(3, 7)
    CXI(0, 2) CXI(1, 3) CXI(4, 6) CXI(5, 7)
    CXI(0, 1) CXI(2, 3) CXI(4, 5) CXI(6, 7)
#undef CXI
#pragma unroll
    for (int m = 0; m < 8; m++) { t8[m] = nv[m]; i8_[m] = ni[m]; }
  }
  const float mx = t8[0];
  float s = 0.f;
#pragma unroll
  for (int m = 0; m < 8; m++) s += expf(t8[m] - mx);
  const float inv = 1.0f / s;

  // lane = output dim d; gather 8 V rows (fp32) and accumulate
  float acc = 0.f;
#pragma unroll
  for (int m = 0; m < 8; m++) {
    const float w = expf(t8[m] - mx) * inv;
    const int j = i8_[m];
    const float vv = (j < NMEM)
        ? mem_v_l[(k * NMEM + j) * DHEAD + lane]
        : kv[(long long)(b * NSEQ + (j - NMEM)) * (2 * NDIM) + NDIM + k * DHEAD + lane];
    acc = fmaf(w, vv, acc);
  }
  const long long orow = (long long)(b * NSEQ + i) * (2 * NDIM) + k * DHEAD + lane;
  bf16 h = (bf16)acc;
  obufs[orow] = h;
  obufs[orow + NDIM] = (bf16)(acc - (float)h);
}

// ---------------------------------------------------------------------------
// fp32 weight (R x C row-major) -> split-transposed bf16 (C x 2R)
// ---------------------------------------------------------------------------
__global__ __launch_bounds__(256)
void transpose_split(const float* __restrict__ in, bf16* __restrict__ out,
                     int R, int C)
{
  const long long idx = (long long)blockIdx.x * 256 + threadIdx.x;
  if (idx >= (long long)R * C) return;
  const int r = (int)(idx / C);
  const int c = (int)(idx % C);
  float v = in[idx];
  bf16 h = (bf16)v;
  out[(long long)c * (2 * R) + r] = h;
  out[(long long)c * (2 * R) + R + r] = (bf16)(v - (float)h);
}

// ---------------------------------------------------------------------------
// T5 bias table; bucket boundaries are exact via log2
// ---------------------------------------------------------------------------
__global__ __launch_bounds__(256)
void build_bias(const float* __restrict__ rel_emb, float* __restrict__ table)
{
  const int idx = blockIdx.x * 256 + threadIdx.x;
  if (idx >= 4111 * 8) return;
  const int h = idx & 7;
  const int rel = (idx >> 3) - 2047;  // rel = j - i
  const int n = -rel;
  const int ret = (n < 0) ? 16 : 0;
  const int na = n < 0 ? -n : n;
  int bucket;
  if (na < 8) {
    bucket = ret + na;
  } else {
    int vl = 8 + (int)(log2((double)na * 0.125) * 2.0);
    vl = vl < 15 ? vl : 15;
    bucket = ret + vl;
  }
  table[idx] = rel_emb[bucket * 8 + h];
}

// ---------------------------------------------------------------------------
extern "C" void kernel_launch(void* const* d_in, const int* in_sizes, int n_in,
                              void* d_out, int out_size, void* d_ws, size_t ws_size,
                              hipStream_t stream)
{
  const float* x_in    = (const float*)d_in[0];
  const float* ln1_g   = (const float*)d_in[1];
  const float* ln1_b   = (const float*)d_in[2];
  const float* Wq      = (const float*)d_in[3];
  const float* Wkv     = (const float*)d_in[4];
  const float* Wo      = (const float*)d_in[5];
  const float* bo      = (const float*)d_in[6];
  const float* pre_proj= (const float*)d_in[7];
  const float* mem_k   = (const float*)d_in[8];
  const float* mem_v   = (const float*)d_in[9];
  const float* ln2_g   = (const float*)d_in[10];
  const float* ln2_b   = (const float*)d_in[11];
  const float* W1      = (const float*)d_in[12];
  const float* b1      = (const float*)d_in[13];
  const float* W2      = (const float*)d_in[14];
  const float* b2      = (const float*)d_in[15];
  const float* rel_emb = (const float*)d_in[16];

  char* p = (char*)d_ws;
  auto alloc = [&](size_t bytes) -> char* {
    char* r = p;
    p += (bytes + 255) & ~(size_t)255;
    return r;
  };

  // ~235 MB total with phase-disjoint aliasing
  float* x    = (float*)alloc((size_t)NROWS * NDIM * 4);          // 8.4 MB
  char*  RA   = alloc((size_t)NROWS * 2 * NDIM * 2);              // 8.4 MB: hs | obufs
  bf16*  hs    = (bf16*)RA;
  bf16*  obufs = (bf16*)RA;
  char*  RB   = alloc((size_t)NROWS * 2 * NFF * 2);               // 33.6 MB: (Qs+Ks) | tbufs
  bf16*  Qs    = (bf16*)RB;                                       // 8.4 MB
  bf16*  Ks    = (bf16*)(RB + (size_t)NROWS * 2 * NDIM * 2);      // 8.9 MB
  bf16*  tbufs = (bf16*)RB;
  float* kv   = (float*)alloc((size_t)NROWS * 2 * NDIM * 4);      // 16.8 MB
  float* S    = (float*)alloc((size_t)NHEADS * PLANE * 4);        // 142.6 MB
  bf16*  WqT  = (bf16*)alloc((size_t)2 * NDIM * 2 * NDIM * 2);
  bf16*  WkvT = (bf16*)alloc((size_t)2 * 2 * NDIM * 2 * NDIM * 2);
  bf16*  WoT  = (bf16*)alloc((size_t)2 * NDIM * 2 * NDIM * 2);
  bf16*  W1T  = (bf16*)alloc((size_t)2 * NFF * 2 * NDIM * 2);
  bf16*  W2T  = (bf16*)alloc((size_t)2 * NDIM * 2 * NFF * 2);
  float* table= (float*)alloc((size_t)4111 * 8 * 4);

  // ---- prep ----
  hipMemcpyAsync(x, x_in, (size_t)NROWS * NDIM * 4, hipMemcpyDeviceToDevice, stream);
  build_bias<<<(4111 * 8 + 255) / 256, 256, 0, stream>>>(rel_emb, table);
  for (int l = 0; l < 2; l++) {
    transpose_split<<<(NDIM * NDIM + 255) / 256, 256, 0, stream>>>(
        Wq + (size_t)l * NDIM * NDIM, WqT + (size_t)l * NDIM * 2 * NDIM, NDIM, NDIM);
    transpose_split<<<(2 * NDIM * NDIM + 255) / 256, 256, 0, stream>>>(
        Wkv + (size_t)l * NDIM * 2 * NDIM, WkvT + (size_t)l * 2 * NDIM * 2 * NDIM, NDIM, 2 * NDIM);
    transpose_split<<<(NDIM * NDIM + 255) / 256, 256, 0, stream>>>(
        Wo + (size_t)l * NDIM * NDIM, WoT + (size_t)l * NDIM * 2 * NDIM, NDIM, NDIM);
    transpose_split<<<(NDIM * NFF + 255) / 256, 256, 0, stream>>>(
        W1 + (size_t)l * NDIM * NFF, W1T + (size_t)l * NFF * 2 * NDIM, NDIM, NFF);
    transpose_split<<<(NFF * NDIM + 255) / 256, 256, 0, stream>>>(
        W2 + (size_t)l * NFF * NDIM, W2T + (size_t)l * NDIM * 2 * NFF, NFF, NDIM);
  }

  // ---- layers ----
  for (int l = 0; l < 2; l++) {
    const bf16* WqT_l  = WqT + (size_t)l * NDIM * 2 * NDIM;
    const bf16* WkvT_l = WkvT + (size_t)l * 2 * NDIM * 2 * NDIM;
    const bf16* WoT_l  = WoT + (size_t)l * NDIM * 2 * NDIM;
    const bf16* W1T_l  = W1T + (size_t)l * NFF * 2 * NDIM;
    const bf16* W2T_l  = W2T + (size_t)l * NDIM * 2 * NFF;
    const float* mem_v_l = mem_v + (size_t)l * NHEADS * NMEM * DHEAD;

    ln_kernel<<<NROWS / 4, 256, 0, stream>>>(x, ln1_g + l * NDIM, ln1_b + l * NDIM, hs);
    // Qs = split(0.125 * h @ Wq)   (scale folded)
    gemm_split<128, 128, 2, 2, EPI_SPLIT><<<dim3(NROWS / 128, NDIM / 128, 1), 256, 0, stream>>>(
        hs, WqT_l, Qs, nullptr, NDIM, 2 * NDIM, 2 * NDIM, NDIM, NDIM, NDIM, 0, 0, 0, 0.125f);
    // kv = h @ Wkv  (fp32)
    gemm_split<128, 128, 2, 2, EPI_F32><<<dim3(NROWS / 128, 2 * NDIM / 128, 1), 256, 0, stream>>>(
        hs, WkvT_l, kv, nullptr, NDIM, 2 * NDIM, 2 * NDIM, 2 * NDIM, NDIM, NDIM, 0, 0, 0, 1.0f);
    build_ks<<<(int)(((long long)NB * NJP * NDIM) / 256), 256, 0, stream>>>(
        kv, mem_k + (size_t)l * NHEADS * NMEM * DHEAD, Ks);

    for (int b = 0; b < NB; b++) {
      // per-head raw scores S_h = q_h . k_h  (K=64, z=8 heads via col offset 64)
      gemm_split<128, 128, 2, 2, EPI_F32><<<dim3(NSEQ / 128, NJP / 128, NHEADS), 256, 0, stream>>>(
          Qs + (size_t)b * NSEQ * 2 * NDIM, Ks + (size_t)b * NJP * 2 * NDIM,
          S, nullptr, DHEAD, 2 * NDIM, 2 * NDIM, NJP, NDIM, NDIM,
          DHEAD, DHEAD, PLANE, 1.0f);
      mix_bias<<<(NSEQ * (NJP / 4)) / 256, 256, 0, stream>>>(S, pre_proj + l * 64, table);
      topk_gather<<<(NHEADS * NSEQ) / 4, 256, 0, stream>>>(S, kv, mem_v_l, obufs, b);
    }

    gemm_split<128, 128, 2, 2, EPI_RESID><<<dim3(NROWS / 128, NDIM / 128, 1), 256, 0, stream>>>(
        obufs, WoT_l, x, bo + l * NDIM, NDIM, 2 * NDIM, 2 * NDIM, NDIM, NDIM, NDIM, 0, 0, 0, 1.0f);

    ln_kernel<<<NROWS / 4, 256, 0, stream>>>(x, ln2_g + l * NDIM, ln2_b + l * NDIM, hs);
    gemm_split<128, 128, 2, 2, EPI_GELUSPLIT><<<dim3(NROWS / 128, NFF / 128, 1), 256, 0, stream>>>(
        hs, W1T_l, tbufs, b1 + l * NFF, NDIM, 2 * NDIM, 2 * NDIM, NFF, NDIM, NDIM, 0, 0, 0, 1.0f);
    gemm_split<128, 128, 2, 2, EPI_RESID><<<dim3(NROWS / 128, NDIM / 128, 1), 256, 0, stream>>>(
        tbufs, W2T_l, x, b2 + l * NDIM, NFF, 2 * NFF, 2 * NFF, NDIM, NFF, NFF, 0, 0, 0, 1.0f);
  }

  hipMemcpyAsync(d_out, x, (size_t)out_size * 4, hipMemcpyDeviceToDevice, stream);
}

// Round 5
// 1078.415 us; speedup vs baseline: 1.6794x; 1.1333x over previous
//
#include <hip/hip_runtime.h>
#include <cmath>

typedef __bf16 bf16;
typedef __attribute__((ext_vector_type(8))) __bf16 bf16x8;
typedef __attribute__((ext_vector_type(4))) __bf16 bf16x4;
typedef __attribute__((ext_vector_type(4))) float f32x4;

#define NB 2
#define NSEQ 2048
#define NDIM 512
#define NHEADS 8
#define DHEAD 64
#define NMEM 16
#define NJ 2064
#define NJP 2176        // 17*128
#define NFF 2048
#define NROWS (NB*NSEQ) // 4096
#define PLANE ((long long)NSEQ * NJP)

enum { EPI_F32 = 0, EPI_SPLIT = 1, EPI_GELUSPLIT = 2, EPI_RESID = 3 };

// ---------------------------------------------------------------------------
// Split-precision GEMM: fp32 operands stored as bf16 (hi,lo). hi at col c,
// lo at col c+loA (A) / c+loB (B). C = Ah*Bh + Al*Bh + Ah*Bl, fp32 accum.
// ---------------------------------------------------------------------------
template<int BM, int BN, int WAVES_M, int WAVES_N, int EPI>
__global__ __launch_bounds__(256)
void gemm_split(const bf16* __restrict__ A, const bf16* __restrict__ B,
                void* __restrict__ Cv, const float* __restrict__ bias,
                int K, int lda, int ldb, int ldc, int loA, int loB,
                long long sAz, long long sBz, long long sCz, float scale)
{
  constexpr int BK = 32;
  constexpr int WM = BM / WAVES_M;
  constexpr int WN = BN / WAVES_N;
  constexpr int MF = WM / 16;
  constexpr int NF = WN / 16;
  constexpr int AI = (BM * BK * 2) / 4096;
  constexpr int BI = (BN * BK * 2) / 4096;
  __shared__ bf16 Ash[BM * BK];
  __shared__ bf16 Asl[BM * BK];
  __shared__ bf16 Bsh[BN * BK];
  __shared__ bf16 Bsl[BN * BK];

  const int z = blockIdx.z;
  A += (long long)z * sAz;
  B += (long long)z * sBz;
  const int bm0 = blockIdx.x * BM;
  const int bn0 = blockIdx.y * BN;
  const int t = threadIdx.x;
  const int wave = t >> 6, lane = t & 63;
  const int wr = wave / WAVES_N, wc = wave % WAVES_N;
  const int sr = t >> 2, sc = t & 3;
  const int frow = lane & 15, fk = (lane >> 4) * 8;

  f32x4 acc[MF][NF] = {};

  for (int k0 = 0; k0 < K; k0 += BK) {
#pragma unroll
    for (int qi = 0; qi < AI; ++qi) {
      const long long ro = (long long)(bm0 + qi * 64 + sr) * lda + (k0 + sc * 8);
      __builtin_amdgcn_global_load_lds(
          (const __attribute__((address_space(1))) void*)(A + ro),
          (__attribute__((address_space(3))) void*)(Ash + qi * 2048 + wave * 512), 16, 0, 0);
      __builtin_amdgcn_global_load_lds(
          (const __attribute__((address_space(1))) void*)(A + ro + loA),
          (__attribute__((address_space(3))) void*)(Asl + qi * 2048 + wave * 512), 16, 0, 0);
    }
#pragma unroll
    for (int qi = 0; qi < BI; ++qi) {
      const long long ro = (long long)(bn0 + qi * 64 + sr) * ldb + (k0 + sc * 8);
      __builtin_amdgcn_global_load_lds(
          (const __attribute__((address_space(1))) void*)(B + ro),
          (__attribute__((address_space(3))) void*)(Bsh + qi * 2048 + wave * 512), 16, 0, 0);
      __builtin_amdgcn_global_load_lds(
          (const __attribute__((address_space(1))) void*)(B + ro + loB),
          (__attribute__((address_space(3))) void*)(Bsl + qi * 2048 + wave * 512), 16, 0, 0);
    }
    __syncthreads();
    bf16x8 afh[MF], afl[MF], bfh[NF], bfl[NF];
#pragma unroll
    for (int m = 0; m < MF; m++) {
      afh[m] = *(const bf16x8*)(Ash + (wr * WM + m * 16 + frow) * BK + fk);
      afl[m] = *(const bf16x8*)(Asl + (wr * WM + m * 16 + frow) * BK + fk);
    }
#pragma unroll
    for (int n = 0; n < NF; n++) {
      bfh[n] = *(const bf16x8*)(Bsh + (wc * WN + n * 16 + frow) * BK + fk);
      bfl[n] = *(const bf16x8*)(Bsl + (wc * WN + n * 16 + frow) * BK + fk);
    }
#pragma unroll
    for (int m = 0; m < MF; m++)
#pragma unroll
      for (int n = 0; n < NF; n++) {
        acc[m][n] = __builtin_amdgcn_mfma_f32_16x16x32_bf16(afh[m], bfh[n], acc[m][n], 0, 0, 0);
        acc[m][n] = __builtin_amdgcn_mfma_f32_16x16x32_bf16(afl[m], bfh[n], acc[m][n], 0, 0, 0);
        acc[m][n] = __builtin_amdgcn_mfma_f32_16x16x32_bf16(afh[m], bfl[n], acc[m][n], 0, 0, 0);
      }
    __syncthreads();
  }

  // C/D layout: col=lane&15, row=(lane>>4)*4+reg
#pragma unroll
  for (int m = 0; m < MF; m++) {
#pragma unroll
    for (int n = 0; n < NF; n++) {
      const int row0 = bm0 + wr * WM + m * 16 + (lane >> 4) * 4;
      const int col = bn0 + wc * WN + n * 16 + (lane & 15);
#pragma unroll
      for (int r = 0; r < 4; r++) {
        const float v = acc[m][n][r] * scale;
        const long long i = row0 + r;
        if (EPI == EPI_F32) {
          (((float*)Cv) + z * sCz)[i * ldc + col] = v;
        } else if (EPI == EPI_SPLIT) {
          bf16* base = ((bf16*)Cv) + z * sCz;
          const long long ih = i * (long long)(2 * ldc) + col;
          bf16 h = (bf16)v;
          base[ih] = h;
          base[ih + ldc] = (bf16)(v - (float)h);
        } else if (EPI == EPI_GELUSPLIT) {
          float u = v + bias[col];
          float gl = 0.5f * u * (1.0f + erff(u * 0.7071067811865476f));
          const long long ih = i * (long long)(2 * ldc) + col;
          bf16 h = (bf16)gl;
          ((bf16*)Cv)[ih] = h;
          ((bf16*)Cv)[ih + ldc] = (bf16)(gl - (float)h);
        } else {  // EPI_RESID
          float* xp = ((float*)Cv) + i * ldc + col;
          *xp = *xp + v + bias[col];
        }
      }
    }
  }
}

// ---------------------------------------------------------------------------
// LayerNorm -> split bf16 (hi | lo), row stride 1024
// ---------------------------------------------------------------------------
__global__ __launch_bounds__(256)
void ln_kernel(const float* __restrict__ x, const float* __restrict__ g,
               const float* __restrict__ b, bf16* __restrict__ out)
{
  const int row = blockIdx.x * 4 + (threadIdx.x >> 6);
  const int lane = threadIdx.x & 63;
  const float* xr = x + (long long)row * NDIM;
  float4 a0 = ((const float4*)xr)[lane];
  float4 a1 = ((const float4*)xr)[lane + 64];
  float s = a0.x + a0.y + a0.z + a0.w + a1.x + a1.y + a1.z + a1.w;
  float ss = a0.x * a0.x + a0.y * a0.y + a0.z * a0.z + a0.w * a0.w
           + a1.x * a1.x + a1.y * a1.y + a1.z * a1.z + a1.w * a1.w;
#pragma unroll
  for (int d = 1; d < 64; d <<= 1) {
    s += __shfl_xor(s, d, 64);
    ss += __shfl_xor(ss, d, 64);
  }
  const float mean = s * (1.0f / NDIM);
  const float var = ss * (1.0f / NDIM) - mean * mean;
  const float rs = rsqrtf(var + 1e-5f);
  float4 g0 = ((const float4*)g)[lane], g1 = ((const float4*)g)[lane + 64];
  float4 b0 = ((const float4*)b)[lane], b1 = ((const float4*)b)[lane + 64];
  bf16* orow = out + (long long)row * (2 * NDIM);
  float y[8] = {
    (a0.x - mean) * rs * g0.x + b0.x, (a0.y - mean) * rs * g0.y + b0.y,
    (a0.z - mean) * rs * g0.z + b0.z, (a0.w - mean) * rs * g0.w + b0.w,
    (a1.x - mean) * rs * g1.x + b1.x, (a1.y - mean) * rs * g1.y + b1.y,
    (a1.z - mean) * rs * g1.z + b1.z, (a1.w - mean) * rs * g1.w + b1.w };
  bf16x4 h0, h1, l0, l1;
#pragma unroll
  for (int j = 0; j < 4; j++) {
    bf16 h = (bf16)y[j];      h0[j] = h;  l0[j] = (bf16)(y[j] - (float)h);
    bf16 h2 = (bf16)y[4 + j]; h1[j] = h2; l1[j] = (bf16)(y[4 + j] - (float)h2);
  }
  *(bf16x4*)(orow + lane * 4) = h0;
  *(bf16x4*)(orow + 256 + lane * 4) = h1;
  *(bf16x4*)(orow + 512 + lane * 4) = l0;
  *(bf16x4*)(orow + 768 + lane * 4) = l1;
}

// ---------------------------------------------------------------------------
// Ks[b][j][c]=hi, [c+512]=lo from kv k-part + mem_k; zero pad rows
// ---------------------------------------------------------------------------
__global__ __launch_bounds__(256)
void build_ks(const float* __restrict__ kv, const float* __restrict__ mem_k_l,
              bf16* __restrict__ Ks)
{
  const long long idx = (long long)blockIdx.x * 256 + threadIdx.x;  // [b][j][c]
  const int c = (int)(idx & 511);
  const int j = (int)((idx >> 9) % NJP);
  const int bb = (int)(idx / ((long long)NJP * NDIM));
  const int h = c >> 6, d = c & 63;
  float kval;
  if (j < NMEM) kval = mem_k_l[(h * NMEM + j) * DHEAD + d];
  else if (j < NJ) kval = kv[(long long)(bb * NSEQ + (j - NMEM)) * (2 * NDIM) + c];
  else kval = 0.f;
  bf16 hv = (bf16)kval;
  const long long ro = ((long long)bb * NJP + j) * (2 * NDIM) + c;
  Ks[ro] = hv;
  Ks[ro + NDIM] = (bf16)(kval - (float)hv);
}

// ---------------------------------------------------------------------------
// Fused talking-heads mix + bias + top-8 + softmax + sparse PV gather.
// Block = 512 threads = 8 waves; blockIdx.x = row i; wave = output head k.
// Each lane scans 34 j-positions: mixed = sum_h pp[h,k]*S[h][i][j] + bias.
// Values-only butterfly -> exact global top-8 values (thr, max, denom).
// Index recovery via ballot over register-resident row; fp32 V gather.
// ---------------------------------------------------------------------------
__global__ __launch_bounds__(512)
void mix_topk_gather(const float* __restrict__ S, const float* __restrict__ kv,
                     const float* __restrict__ mem_v_l, const float* __restrict__ pp,
                     const float* __restrict__ table, bf16* __restrict__ obufs,
                     int b)
{
  const int i = blockIdx.x;
  const int k = threadIdx.x >> 6;
  const int lane = threadIdx.x & 63;
  float pk[8];
#pragma unroll
  for (int h = 0; h < 8; h++) pk[h] = pp[h * 8 + k];
  const float* base = S + (long long)i * NJP;

  float v[34];
  float t8[8];
#pragma unroll
  for (int m = 0; m < 8; m++) t8[m] = -3.0e38f;
#pragma unroll
  for (int t = 0; t < 34; t++) {
    const int j = lane + 64 * t;
    float xv;
    if (j < NJ) {
      xv = table[(j - i + 2047) * 8 + k];
#pragma unroll
      for (int h = 0; h < 8; h++)
        xv = fmaf(base[(long long)h * PLANE + j], pk[h], xv);
    } else {
      xv = -1e30f;
    }
    v[t] = xv;
    if (xv > t8[7]) {
      t8[7] = xv;
#pragma unroll
      for (int m = 6; m >= 0; m--)
        if (t8[m + 1] > t8[m]) { float tv = t8[m]; t8[m] = t8[m + 1]; t8[m + 1] = tv; }
    }
  }
  // values-only butterfly: global top-8 (sorted desc) in every lane
#pragma unroll
  for (int d = 1; d < 64; d <<= 1) {
    float o[8], m8[8];
#pragma unroll
    for (int m = 0; m < 8; m++) o[m] = __shfl_xor(t8[m], d, 64);
#pragma unroll
    for (int m = 0; m < 8; m++) m8[m] = fmaxf(t8[m], o[7 - m]);
#define CX(a, bq) { float hi = fmaxf(m8[a], m8[bq]); float lo = fminf(m8[a], m8[bq]); m8[a] = hi; m8[bq] = lo; }
    CX(0, 4) CX(1, 5) CX(2, 6) CX(3, 7)
    CX(0, 2) CX(1, 3) CX(4, 6) CX(5, 7)
    CX(0, 1) CX(2, 3) CX(4, 5) CX(6, 7)
#undef CX
#pragma unroll
    for (int m = 0; m < 8; m++) t8[m] = m8[m];
  }
  const float mx = t8[0];
  const float thr = t8[7];
  float denom = 0.f;
#pragma unroll
  for (int m = 0; m < 8; m++) denom += expf(t8[m] - mx);
  const float inv = 1.0f / denom;

  // index recovery + gather: ~8 hits total across the row
  float acc = 0.f;
#pragma unroll
  for (int t = 0; t < 34; t++) {
    unsigned long long m = __ballot(v[t] >= thr);
    while (m) {
      const int l = __builtin_ctzll((unsigned long long)m);
      m &= m - 1;
      const int jj = l + 64 * t;
      const float sv = __shfl(v[t], l);
      const float w = expf(sv - mx) * inv;
      const float vv = (jj < NMEM)
          ? mem_v_l[(k * NMEM + jj) * DHEAD + lane]
          : kv[(long long)(b * NSEQ + (jj - NMEM)) * (2 * NDIM) + NDIM + k * DHEAD + lane];
      acc = fmaf(w, vv, acc);
    }
  }
  const long long orow = (long long)(b * NSEQ + i) * (2 * NDIM) + k * DHEAD + lane;
  bf16 h = (bf16)acc;
  obufs[orow] = h;
  obufs[orow + NDIM] = (bf16)(acc - (float)h);
}

// ---------------------------------------------------------------------------
// fp32 weight (R x C row-major) -> split-transposed bf16 (C x 2R)
// ---------------------------------------------------------------------------
__global__ __launch_bounds__(256)
void transpose_split(const float* __restrict__ in, bf16* __restrict__ out,
                     int R, int C)
{
  const long long idx = (long long)blockIdx.x * 256 + threadIdx.x;
  if (idx >= (long long)R * C) return;
  const int r = (int)(idx / C);
  const int c = (int)(idx % C);
  float v = in[idx];
  bf16 h = (bf16)v;
  out[(long long)c * (2 * R) + r] = h;
  out[(long long)c * (2 * R) + R + r] = (bf16)(v - (float)h);
}

// ---------------------------------------------------------------------------
// T5 bias table; bucket boundaries are exact via log2
// ---------------------------------------------------------------------------
__global__ __launch_bounds__(256)
void build_bias(const float* __restrict__ rel_emb, float* __restrict__ table)
{
  const int idx = blockIdx.x * 256 + threadIdx.x;
  if (idx >= 4111 * 8) return;
  const int h = idx & 7;
  const int rel = (idx >> 3) - 2047;  // rel = j - i
  const int n = -rel;
  const int ret = (n < 0) ? 16 : 0;
  const int na = n < 0 ? -n : n;
  int bucket;
  if (na < 8) {
    bucket = ret + na;
  } else {
    int vl = 8 + (int)(log2((double)na * 0.125) * 2.0);
    vl = vl < 15 ? vl : 15;
    bucket = ret + vl;
  }
  table[idx] = rel_emb[bucket * 8 + h];
}

// ---------------------------------------------------------------------------
extern "C" void kernel_launch(void* const* d_in, const int* in_sizes, int n_in,
                              void* d_out, int out_size, void* d_ws, size_t ws_size,
                              hipStream_t stream)
{
  const float* x_in    = (const float*)d_in[0];
  const float* ln1_g   = (const float*)d_in[1];
  const float* ln1_b   = (const float*)d_in[2];
  const float* Wq      = (const float*)d_in[3];
  const float* Wkv     = (const float*)d_in[4];
  const float* Wo      = (const float*)d_in[5];
  const float* bo      = (const float*)d_in[6];
  const float* pre_proj= (const float*)d_in[7];
  const float* mem_k   = (const float*)d_in[8];
  const float* mem_v   = (const float*)d_in[9];
  const float* ln2_g   = (const float*)d_in[10];
  const float* ln2_b   = (const float*)d_in[11];
  const float* W1      = (const float*)d_in[12];
  const float* b1      = (const float*)d_in[13];
  const float* W2      = (const float*)d_in[14];
  const float* b2      = (const float*)d_in[15];
  const float* rel_emb = (const float*)d_in[16];

  char* p = (char*)d_ws;
  auto alloc = [&](size_t bytes) -> char* {
    char* r = p;
    p += (bytes + 255) & ~(size_t)255;
    return r;
  };

  // ~235 MB total with phase-disjoint aliasing
  float* x    = (float*)alloc((size_t)NROWS * NDIM * 4);          // 8.4 MB
  char*  RA   = alloc((size_t)NROWS * 2 * NDIM * 2);              // 8.4 MB: hs | obufs
  bf16*  hs    = (bf16*)RA;
  bf16*  obufs = (bf16*)RA;
  char*  RB   = alloc((size_t)NROWS * 2 * NFF * 2);               // 33.6 MB: (Qs+Ks) | tbufs
  bf16*  Qs    = (bf16*)RB;                                       // 8.4 MB
  bf16*  Ks    = (bf16*)(RB + (size_t)NROWS * 2 * NDIM * 2);      // 8.9 MB
  bf16*  tbufs = (bf16*)RB;
  float* kv   = (float*)alloc((size_t)NROWS * 2 * NDIM * 4);      // 16.8 MB
  float* S    = (float*)alloc((size_t)NHEADS * PLANE * 4);        // 142.6 MB
  bf16*  WqT  = (bf16*)alloc((size_t)2 * NDIM * 2 * NDIM * 2);
  bf16*  WkvT = (bf16*)alloc((size_t)2 * 2 * NDIM * 2 * NDIM * 2);
  bf16*  WoT  = (bf16*)alloc((size_t)2 * NDIM * 2 * NDIM * 2);
  bf16*  W1T  = (bf16*)alloc((size_t)2 * NFF * 2 * NDIM * 2);
  bf16*  W2T  = (bf16*)alloc((size_t)2 * NDIM * 2 * NFF * 2);
  float* table= (float*)alloc((size_t)4111 * 8 * 4);

  // ---- prep ----
  hipMemcpyAsync(x, x_in, (size_t)NROWS * NDIM * 4, hipMemcpyDeviceToDevice, stream);
  build_bias<<<(4111 * 8 + 255) / 256, 256, 0, stream>>>(rel_emb, table);
  for (int l = 0; l < 2; l++) {
    transpose_split<<<(NDIM * NDIM + 255) / 256, 256, 0, stream>>>(
        Wq + (size_t)l * NDIM * NDIM, WqT + (size_t)l * NDIM * 2 * NDIM, NDIM, NDIM);
    transpose_split<<<(2 * NDIM * NDIM + 255) / 256, 256, 0, stream>>>(
        Wkv + (size_t)l * NDIM * 2 * NDIM, WkvT + (size_t)l * 2 * NDIM * 2 * NDIM, NDIM, 2 * NDIM);
    transpose_split<<<(NDIM * NDIM + 255) / 256, 256, 0, stream>>>(
        Wo + (size_t)l * NDIM * NDIM, WoT + (size_t)l * NDIM * 2 * NDIM, NDIM, NDIM);
    transpose_split<<<(NDIM * NFF + 255) / 256, 256, 0, stream>>>(
        W1 + (size_t)l * NDIM * NFF, W1T + (size_t)l * NFF * 2 * NDIM, NDIM, NFF);
    transpose_split<<<(NFF * NDIM + 255) / 256, 256, 0, stream>>>(
        W2 + (size_t)l * NFF * NDIM, W2T + (size_t)l * NDIM * 2 * NFF, NFF, NDIM);
  }

  // ---- layers ----
  for (int l = 0; l < 2; l++) {
    const bf16* WqT_l  = WqT + (size_t)l * NDIM * 2 * NDIM;
    const bf16* WkvT_l = WkvT + (size_t)l * 2 * NDIM * 2 * NDIM;
    const bf16* WoT_l  = WoT + (size_t)l * NDIM * 2 * NDIM;
    const bf16* W1T_l  = W1T + (size_t)l * NFF * 2 * NDIM;
    const bf16* W2T_l  = W2T + (size_t)l * NDIM * 2 * NFF;
    const float* mem_v_l = mem_v + (size_t)l * NHEADS * NMEM * DHEAD;

    ln_kernel<<<NROWS / 4, 256, 0, stream>>>(x, ln1_g + l * NDIM, ln1_b + l * NDIM, hs);
    // Qs = split(0.125 * h @ Wq)   (scale folded)
    gemm_split<128, 128, 2, 2, EPI_SPLIT><<<dim3(NROWS / 128, NDIM / 128, 1), 256, 0, stream>>>(
        hs, WqT_l, Qs, nullptr, NDIM, 2 * NDIM, 2 * NDIM, NDIM, NDIM, NDIM, 0, 0, 0, 0.125f);
    // kv = h @ Wkv  (fp32)
    gemm_split<128, 128, 2, 2, EPI_F32><<<dim3(NROWS / 128, 2 * NDIM / 128, 1), 256, 0, stream>>>(
        hs, WkvT_l, kv, nullptr, NDIM, 2 * NDIM, 2 * NDIM, 2 * NDIM, NDIM, NDIM, 0, 0, 0, 1.0f);
    build_ks<<<(int)(((long long)NB * NJP * NDIM) / 256), 256, 0, stream>>>(
        kv, mem_k + (size_t)l * NHEADS * NMEM * DHEAD, Ks);

    for (int b = 0; b < NB; b++) {
      // per-head raw scores S_h = q_h . k_h  (K=64, z=8 heads via col offset 64)
      gemm_split<128, 128, 2, 2, EPI_F32><<<dim3(NSEQ / 128, NJP / 128, NHEADS), 256, 0, stream>>>(
          Qs + (size_t)b * NSEQ * 2 * NDIM, Ks + (size_t)b * NJP * 2 * NDIM,
          S, nullptr, DHEAD, 2 * NDIM, 2 * NDIM, NJP, NDIM, NDIM,
          DHEAD, DHEAD, PLANE, 1.0f);
      mix_topk_gather<<<NSEQ, 512, 0, stream>>>(
          S, kv, mem_v_l, pre_proj + l * 64, table, obufs, b);
    }

    gemm_split<128, 128, 2, 2, EPI_RESID><<<dim3(NROWS / 128, NDIM / 128, 1), 256, 0, stream>>>(
        obufs, WoT_l, x, bo + l * NDIM, NDIM, 2 * NDIM, 2 * NDIM, NDIM, NDIM, NDIM, 0, 0, 0, 1.0f);

    ln_kernel<<<NROWS / 4, 256, 0, stream>>>(x, ln2_g + l * NDIM, ln2_b + l * NDIM, hs);
    gemm_split<128, 128, 2, 2, EPI_GELUSPLIT><<<dim3(NROWS / 128, NFF / 128, 1), 256, 0, stream>>>(
        hs, W1T_l, tbufs, b1 + l * NFF, NDIM, 2 * NDIM, 2 * NDIM, NFF, NDIM, NDIM, 0, 0, 0, 1.0f);
    gemm_split<128, 128, 2, 2, EPI_RESID><<<dim3(NROWS / 128, NDIM / 128, 1), 256, 0, stream>>>(
        tbufs, W2T_l, x, b2 + l * NDIM, NFF, 2 * NFF, 2 * NFF, NDIM, NFF, NFF, 0, 0, 0, 1.0f);
  }

  hipMemcpyAsync(d_out, x, (size_t)out_size * 4, hipMemcpyDeviceToDevice, stream);
}

// Round 6
// 1067.335 us; speedup vs baseline: 1.6968x; 1.0104x over previous
//
#include <hip/hip_runtime.h>
#include <cmath>

typedef __bf16 bf16;
typedef __attribute__((ext_vector_type(8))) __bf16 bf16x8;
typedef __attribute__((ext_vector_type(4))) __bf16 bf16x4;
typedef __attribute__((ext_vector_type(4))) float f32x4;

#define NB 2
#define NSEQ 2048
#define NDIM 512
#define NHEADS 8
#define DHEAD 64
#define NMEM 16
#define NJ 2064
#define NJP 2176        // 17*128
#define NFF 2048
#define NROWS (NB*NSEQ) // 4096
#define PLANE ((long long)NSEQ * NJP)

enum { EPI_F32 = 0, EPI_SPLIT = 1, EPI_GELUSPLIT = 2, EPI_RESID = 3 };

// ---------------------------------------------------------------------------
// Split-precision GEMM: fp32 operands stored as bf16 (hi,lo). hi at col c,
// lo at col c+loA (A) / c+loB (B). C = Ah*Bh + Al*Bh + Ah*Bl, fp32 accum.
// ---------------------------------------------------------------------------
template<int BM, int BN, int WAVES_M, int WAVES_N, int EPI>
__global__ __launch_bounds__(256)
void gemm_split(const bf16* __restrict__ A, const bf16* __restrict__ B,
                void* __restrict__ Cv, const float* __restrict__ bias,
                int K, int lda, int ldb, int ldc, int loA, int loB,
                long long sAz, long long sBz, long long sCz, float scale)
{
  constexpr int BK = 32;
  constexpr int WM = BM / WAVES_M;
  constexpr int WN = BN / WAVES_N;
  constexpr int MF = WM / 16;
  constexpr int NF = WN / 16;
  constexpr int AI = (BM * BK * 2) / 4096;
  constexpr int BI = (BN * BK * 2) / 4096;
  __shared__ bf16 Ash[BM * BK];
  __shared__ bf16 Asl[BM * BK];
  __shared__ bf16 Bsh[BN * BK];
  __shared__ bf16 Bsl[BN * BK];

  const int z = blockIdx.z;
  A += (long long)z * sAz;
  B += (long long)z * sBz;
  const int bm0 = blockIdx.x * BM;
  const int bn0 = blockIdx.y * BN;
  const int t = threadIdx.x;
  const int wave = t >> 6, lane = t & 63;
  const int wr = wave / WAVES_N, wc = wave % WAVES_N;
  const int sr = t >> 2, sc = t & 3;
  const int frow = lane & 15, fk = (lane >> 4) * 8;

  f32x4 acc[MF][NF] = {};

  for (int k0 = 0; k0 < K; k0 += BK) {
#pragma unroll
    for (int qi = 0; qi < AI; ++qi) {
      const long long ro = (long long)(bm0 + qi * 64 + sr) * lda + (k0 + sc * 8);
      __builtin_amdgcn_global_load_lds(
          (const __attribute__((address_space(1))) void*)(A + ro),
          (__attribute__((address_space(3))) void*)(Ash + qi * 2048 + wave * 512), 16, 0, 0);
      __builtin_amdgcn_global_load_lds(
          (const __attribute__((address_space(1))) void*)(A + ro + loA),
          (__attribute__((address_space(3))) void*)(Asl + qi * 2048 + wave * 512), 16, 0, 0);
    }
#pragma unroll
    for (int qi = 0; qi < BI; ++qi) {
      const long long ro = (long long)(bn0 + qi * 64 + sr) * ldb + (k0 + sc * 8);
      __builtin_amdgcn_global_load_lds(
          (const __attribute__((address_space(1))) void*)(B + ro),
          (__attribute__((address_space(3))) void*)(Bsh + qi * 2048 + wave * 512), 16, 0, 0);
      __builtin_amdgcn_global_load_lds(
          (const __attribute__((address_space(1))) void*)(B + ro + loB),
          (__attribute__((address_space(3))) void*)(Bsl + qi * 2048 + wave * 512), 16, 0, 0);
    }
    __syncthreads();
    bf16x8 afh[MF], afl[MF], bfh[NF], bfl[NF];
#pragma unroll
    for (int m = 0; m < MF; m++) {
      afh[m] = *(const bf16x8*)(Ash + (wr * WM + m * 16 + frow) * BK + fk);
      afl[m] = *(const bf16x8*)(Asl + (wr * WM + m * 16 + frow) * BK + fk);
    }
#pragma unroll
    for (int n = 0; n < NF; n++) {
      bfh[n] = *(const bf16x8*)(Bsh + (wc * WN + n * 16 + frow) * BK + fk);
      bfl[n] = *(const bf16x8*)(Bsl + (wc * WN + n * 16 + frow) * BK + fk);
    }
#pragma unroll
    for (int m = 0; m < MF; m++)
#pragma unroll
      for (int n = 0; n < NF; n++) {
        acc[m][n] = __builtin_amdgcn_mfma_f32_16x16x32_bf16(afh[m], bfh[n], acc[m][n], 0, 0, 0);
        acc[m][n] = __builtin_amdgcn_mfma_f32_16x16x32_bf16(afl[m], bfh[n], acc[m][n], 0, 0, 0);
        acc[m][n] = __builtin_amdgcn_mfma_f32_16x16x32_bf16(afh[m], bfl[n], acc[m][n], 0, 0, 0);
      }
    __syncthreads();
  }

  // C/D layout: col=lane&15, row=(lane>>4)*4+reg
#pragma unroll
  for (int m = 0; m < MF; m++) {
#pragma unroll
    for (int n = 0; n < NF; n++) {
      const int row0 = bm0 + wr * WM + m * 16 + (lane >> 4) * 4;
      const int col = bn0 + wc * WN + n * 16 + (lane & 15);
#pragma unroll
      for (int r = 0; r < 4; r++) {
        const float v = acc[m][n][r] * scale;
        const long long i = row0 + r;
        if (EPI == EPI_F32) {
          (((float*)Cv) + z * sCz)[i * ldc + col] = v;
        } else if (EPI == EPI_SPLIT) {
          bf16* base = ((bf16*)Cv) + z * sCz;
          const long long ih = i * (long long)(2 * ldc) + col;
          bf16 h = (bf16)v;
          base[ih] = h;
          base[ih + ldc] = (bf16)(v - (float)h);
        } else if (EPI == EPI_GELUSPLIT) {
          float u = v + bias[col];
          float gl = 0.5f * u * (1.0f + erff(u * 0.7071067811865476f));
          const long long ih = i * (long long)(2 * ldc) + col;
          bf16 h = (bf16)gl;
          ((bf16*)Cv)[ih] = h;
          ((bf16*)Cv)[ih + ldc] = (bf16)(gl - (float)h);
        } else {  // EPI_RESID
          float* xp = ((float*)Cv) + i * ldc + col;
          *xp = *xp + v + bias[col];
        }
      }
    }
  }
}

// ---------------------------------------------------------------------------
// LayerNorm -> split bf16 (hi | lo), row stride 1024
// ---------------------------------------------------------------------------
__global__ __launch_bounds__(256)
void ln_kernel(const float* __restrict__ x, const float* __restrict__ g,
               const float* __restrict__ b, bf16* __restrict__ out)
{
  const int row = blockIdx.x * 4 + (threadIdx.x >> 6);
  const int lane = threadIdx.x & 63;
  const float* xr = x + (long long)row * NDIM;
  float4 a0 = ((const float4*)xr)[lane];
  float4 a1 = ((const float4*)xr)[lane + 64];
  float s = a0.x + a0.y + a0.z + a0.w + a1.x + a1.y + a1.z + a1.w;
  float ss = a0.x * a0.x + a0.y * a0.y + a0.z * a0.z + a0.w * a0.w
           + a1.x * a1.x + a1.y * a1.y + a1.z * a1.z + a1.w * a1.w;
#pragma unroll
  for (int d = 1; d < 64; d <<= 1) {
    s += __shfl_xor(s, d, 64);
    ss += __shfl_xor(ss, d, 64);
  }
  const float mean = s * (1.0f / NDIM);
  const float var = ss * (1.0f / NDIM) - mean * mean;
  const float rs = rsqrtf(var + 1e-5f);
  float4 g0 = ((const float4*)g)[lane], g1 = ((const float4*)g)[lane + 64];
  float4 b0 = ((const float4*)b)[lane], b1 = ((const float4*)b)[lane + 64];
  bf16* orow = out + (long long)row * (2 * NDIM);
  float y[8] = {
    (a0.x - mean) * rs * g0.x + b0.x, (a0.y - mean) * rs * g0.y + b0.y,
    (a0.z - mean) * rs * g0.z + b0.z, (a0.w - mean) * rs * g0.w + b0.w,
    (a1.x - mean) * rs * g1.x + b1.x, (a1.y - mean) * rs * g1.y + b1.y,
    (a1.z - mean) * rs * g1.z + b1.z, (a1.w - mean) * rs * g1.w + b1.w };
  bf16x4 h0, h1, l0, l1;
#pragma unroll
  for (int j = 0; j < 4; j++) {
    bf16 h = (bf16)y[j];      h0[j] = h;  l0[j] = (bf16)(y[j] - (float)h);
    bf16 h2 = (bf16)y[4 + j]; h1[j] = h2; l1[j] = (bf16)(y[4 + j] - (float)h2);
  }
  *(bf16x4*)(orow + lane * 4) = h0;
  *(bf16x4*)(orow + 256 + lane * 4) = h1;
  *(bf16x4*)(orow + 512 + lane * 4) = l0;
  *(bf16x4*)(orow + 768 + lane * 4) = l1;
}

// ---------------------------------------------------------------------------
// Ks[b][j][c]=hi, [c+512]=lo from kv k-part + mem_k; zero pad rows
// ---------------------------------------------------------------------------
__global__ __launch_bounds__(256)
void build_ks(const float* __restrict__ kv, const float* __restrict__ mem_k_l,
              bf16* __restrict__ Ks)
{
  const long long idx = (long long)blockIdx.x * 256 + threadIdx.x;  // [b][j][c]
  const int c = (int)(idx & 511);
  const int j = (int)((idx >> 9) % NJP);
  const int bb = (int)(idx / ((long long)NJP * NDIM));
  const int h = c >> 6, d = c & 63;
  float kval;
  if (j < NMEM) kval = mem_k_l[(h * NMEM + j) * DHEAD + d];
  else if (j < NJ) kval = kv[(long long)(bb * NSEQ + (j - NMEM)) * (2 * NDIM) + c];
  else kval = 0.f;
  bf16 hv = (bf16)kval;
  const long long ro = ((long long)bb * NJP + j) * (2 * NDIM) + c;
  Ks[ro] = hv;
  Ks[ro + NDIM] = (bf16)(kval - (float)hv);
}

// ---------------------------------------------------------------------------
// Fused talking-heads mix + bias + top-8 + softmax + sparse PV gather.
// Block = 512 threads = 8 waves; blockIdx.x = row i; wave = output head k.
// Lane owns 4 consecutive j per iter (dwordx4 plane loads), 8 iters + 2-tail.
// Branchless sorted insertion (no divergence), values-only butterfly merge,
// ballot-based index recovery, fp32 V gather, split-bf16 output.
// ---------------------------------------------------------------------------
__global__ __launch_bounds__(512)
void mix_topk_gather(const float* __restrict__ S, const float* __restrict__ kv,
                     const float* __restrict__ mem_v_l, const float* __restrict__ pp,
                     const float* __restrict__ table, bf16* __restrict__ obufs,
                     int b)
{
  const int i = blockIdx.x;
  const int k = threadIdx.x >> 6;
  const int lane = threadIdx.x & 63;
  float pk[8];
#pragma unroll
  for (int h = 0; h < 8; h++) pk[h] = pp[h * 8 + k];
  const float* base = S + (long long)i * NJP;

  float v[34];
  float t8[8];
#pragma unroll
  for (int m = 0; m < 8; m++) t8[m] = -3.0e38f;

#pragma unroll
  for (int t = 0; t < 8; t++) {
    const int j0 = 256 * t + 4 * lane;              // j0..j0+3, all < 2048 (valid)
    const float* tb = table + (j0 - i + 2047) * 8 + k;
    float4 a;
    a.x = tb[0]; a.y = tb[8]; a.z = tb[16]; a.w = tb[24];
#pragma unroll
    for (int h = 0; h < 8; h++) {
      const float4 s4 = *(const float4*)(base + (long long)h * PLANE + j0);
      a.x = fmaf(s4.x, pk[h], a.x);
      a.y = fmaf(s4.y, pk[h], a.y);
      a.z = fmaf(s4.z, pk[h], a.z);
      a.w = fmaf(s4.w, pk[h], a.w);
    }
    v[t * 4 + 0] = a.x; v[t * 4 + 1] = a.y; v[t * 4 + 2] = a.z; v[t * 4 + 3] = a.w;
    // branchless descending insertion
#pragma unroll
    for (int e = 0; e < 4; e++) {
      float x = v[t * 4 + e];
#pragma unroll
      for (int m = 0; m < 8; m++) {
        const float hi = fmaxf(t8[m], x);
        x = fminf(t8[m], x);
        t8[m] = hi;
      }
    }
  }
  // tail: j = 2048 + 2*lane (+1); valid only for lanes 0..7 (j < 2064)
  {
    const int j0 = 2048 + 2 * lane;
    const int jc = j0 < 2062 ? j0 : 2062;           // keep table reads in-bounds
    const float* tb = table + (jc - i + 2047) * 8 + k;
    float ax = tb[0], ay = tb[8];
#pragma unroll
    for (int h = 0; h < 8; h++) {
      const float2 s2 = *(const float2*)(base + (long long)h * PLANE + j0);
      ax = fmaf(s2.x, pk[h], ax);
      ay = fmaf(s2.y, pk[h], ay);
    }
    v[32] = (j0 < NJ) ? ax : -1e30f;
    v[33] = (j0 + 1 < NJ) ? ay : -1e30f;
#pragma unroll
    for (int e = 32; e < 34; e++) {
      float x = v[e];
#pragma unroll
      for (int m = 0; m < 8; m++) {
        const float hi = fmaxf(t8[m], x);
        x = fminf(t8[m], x);
        t8[m] = hi;
      }
    }
  }

  // values-only butterfly: global top-8 (sorted desc) in every lane
#pragma unroll
  for (int d = 1; d < 64; d <<= 1) {
    float o[8], m8[8];
#pragma unroll
    for (int m = 0; m < 8; m++) o[m] = __shfl_xor(t8[m], d, 64);
#pragma unroll
    for (int m = 0; m < 8; m++) m8[m] = fmaxf(t8[m], o[7 - m]);
#define CX(a, bq) { float hi = fmaxf(m8[a], m8[bq]); float lo = fminf(m8[a], m8[bq]); m8[a] = hi; m8[bq] = lo; }
    CX(0, 4) CX(1, 5) CX(2, 6) CX(3, 7)
    CX(0, 2) CX(1, 3) CX(4, 6) CX(5, 7)
    CX(0, 1) CX(2, 3) CX(4, 5) CX(6, 7)
#undef CX
#pragma unroll
    for (int m = 0; m < 8; m++) t8[m] = m8[m];
  }
  const float mx = t8[0];
  const float thr = t8[7];
  float denom = 0.f;
#pragma unroll
  for (int m = 0; m < 8; m++) denom += expf(t8[m] - mx);
  const float inv = 1.0f / denom;

  // index recovery + gather (~8 hits total; ballot loops are wave-uniform)
  float acc = 0.f;
#pragma unroll
  for (int t = 0; t < 8; t++) {
#pragma unroll
    for (int e = 0; e < 4; e++) {
      unsigned long long mball = __ballot(v[t * 4 + e] >= thr);
      while (mball) {
        const int l = __builtin_ctzll(mball);
        mball &= mball - 1;
        const int jj = 256 * t + 4 * l + e;
        const float sv = __shfl(v[t * 4 + e], l);
        const float w = expf(sv - mx) * inv;
        const float vv = (jj < NMEM)
            ? mem_v_l[(k * NMEM + jj) * DHEAD + lane]
            : kv[(long long)(b * NSEQ + (jj - NMEM)) * (2 * NDIM) + NDIM + k * DHEAD + lane];
        acc = fmaf(w, vv, acc);
      }
    }
  }
#pragma unroll
  for (int e = 0; e < 2; e++) {
    unsigned long long mball = __ballot(v[32 + e] >= thr);
    while (mball) {
      const int l = __builtin_ctzll(mball);
      mball &= mball - 1;
      const int jj = 2048 + 2 * l + e;
      const float sv = __shfl(v[32 + e], l);
      const float w = expf(sv - mx) * inv;
      const float vv = (jj < NMEM)
          ? mem_v_l[(k * NMEM + jj) * DHEAD + lane]
          : kv[(long long)(b * NSEQ + (jj - NMEM)) * (2 * NDIM) + NDIM + k * DHEAD + lane];
      acc = fmaf(w, vv, acc);
    }
  }

  const long long orow = (long long)(b * NSEQ + i) * (2 * NDIM) + k * DHEAD + lane;
  bf16 h = (bf16)acc;
  obufs[orow] = h;
  obufs[orow + NDIM] = (bf16)(acc - (float)h);
}

// ---------------------------------------------------------------------------
// fp32 weight (R x C row-major) -> split-transposed bf16 (C x 2R)
// ---------------------------------------------------------------------------
__global__ __launch_bounds__(256)
void transpose_split(const float* __restrict__ in, bf16* __restrict__ out,
                     int R, int C)
{
  const long long idx = (long long)blockIdx.x * 256 + threadIdx.x;
  if (idx >= (long long)R * C) return;
  const int r = (int)(idx / C);
  const int c = (int)(idx % C);
  float v = in[idx];
  bf16 h = (bf16)v;
  out[(long long)c * (2 * R) + r] = h;
  out[(long long)c * (2 * R) + R + r] = (bf16)(v - (float)h);
}

// ---------------------------------------------------------------------------
// T5 bias table; bucket boundaries are exact via log2
// ---------------------------------------------------------------------------
__global__ __launch_bounds__(256)
void build_bias(const float* __restrict__ rel_emb, float* __restrict__ table)
{
  const int idx = blockIdx.x * 256 + threadIdx.x;
  if (idx >= 4111 * 8) return;
  const int h = idx & 7;
  const int rel = (idx >> 3) - 2047;  // rel = j - i
  const int n = -rel;
  const int ret = (n < 0) ? 16 : 0;
  const int na = n < 0 ? -n : n;
  int bucket;
  if (na < 8) {
    bucket = ret + na;
  } else {
    int vl = 8 + (int)(log2((double)na * 0.125) * 2.0);
    vl = vl < 15 ? vl : 15;
    bucket = ret + vl;
  }
  table[idx] = rel_emb[bucket * 8 + h];
}

// ---------------------------------------------------------------------------
extern "C" void kernel_launch(void* const* d_in, const int* in_sizes, int n_in,
                              void* d_out, int out_size, void* d_ws, size_t ws_size,
                              hipStream_t stream)
{
  const float* x_in    = (const float*)d_in[0];
  const float* ln1_g   = (const float*)d_in[1];
  const float* ln1_b   = (const float*)d_in[2];
  const float* Wq      = (const float*)d_in[3];
  const float* Wkv     = (const float*)d_in[4];
  const float* Wo      = (const float*)d_in[5];
  const float* bo      = (const float*)d_in[6];
  const float* pre_proj= (const float*)d_in[7];
  const float* mem_k   = (const float*)d_in[8];
  const float* mem_v   = (const float*)d_in[9];
  const float* ln2_g   = (const float*)d_in[10];
  const float* ln2_b   = (const float*)d_in[11];
  const float* W1      = (const float*)d_in[12];
  const float* b1      = (const float*)d_in[13];
  const float* W2      = (const float*)d_in[14];
  const float* b2      = (const float*)d_in[15];
  const float* rel_emb = (const float*)d_in[16];

  char* p = (char*)d_ws;
  auto alloc = [&](size_t bytes) -> char* {
    char* r = p;
    p += (bytes + 255) & ~(size_t)255;
    return r;
  };

  // ~235 MB total with phase-disjoint aliasing
  float* x    = (float*)alloc((size_t)NROWS * NDIM * 4);          // 8.4 MB
  char*  RA   = alloc((size_t)NROWS * 2 * NDIM * 2);              // 8.4 MB: hs | obufs
  bf16*  hs    = (bf16*)RA;
  bf16*  obufs = (bf16*)RA;
  char*  RB   = alloc((size_t)NROWS * 2 * NFF * 2);               // 33.6 MB: (Qs+Ks) | tbufs
  bf16*  Qs    = (bf16*)RB;                                       // 8.4 MB
  bf16*  Ks    = (bf16*)(RB + (size_t)NROWS * 2 * NDIM * 2);      // 8.9 MB
  bf16*  tbufs = (bf16*)RB;
  float* kv   = (float*)alloc((size_t)NROWS * 2 * NDIM * 4);      // 16.8 MB
  float* S    = (float*)alloc((size_t)NHEADS * PLANE * 4);        // 142.6 MB
  bf16*  WqT  = (bf16*)alloc((size_t)2 * NDIM * 2 * NDIM * 2);
  bf16*  WkvT = (bf16*)alloc((size_t)2 * 2 * NDIM * 2 * NDIM * 2);
  bf16*  WoT  = (bf16*)alloc((size_t)2 * NDIM * 2 * NDIM * 2);
  bf16*  W1T  = (bf16*)alloc((size_t)2 * NFF * 2 * NDIM * 2);
  bf16*  W2T  = (bf16*)alloc((size_t)2 * NDIM * 2 * NFF * 2);
  float* table= (float*)alloc((size_t)4111 * 8 * 4);

  // ---- prep ----
  hipMemcpyAsync(x, x_in, (size_t)NROWS * NDIM * 4, hipMemcpyDeviceToDevice, stream);
  build_bias<<<(4111 * 8 + 255) / 256, 256, 0, stream>>>(rel_emb, table);
  for (int l = 0; l < 2; l++) {
    transpose_split<<<(NDIM * NDIM + 255) / 256, 256, 0, stream>>>(
        Wq + (size_t)l * NDIM * NDIM, WqT + (size_t)l * NDIM * 2 * NDIM, NDIM, NDIM);
    transpose_split<<<(2 * NDIM * NDIM + 255) / 256, 256, 0, stream>>>(
        Wkv + (size_t)l * NDIM * 2 * NDIM, WkvT + (size_t)l * 2 * NDIM * 2 * NDIM, NDIM, 2 * NDIM);
    transpose_split<<<(NDIM * NDIM + 255) / 256, 256, 0, stream>>>(
        Wo + (size_t)l * NDIM * NDIM, WoT + (size_t)l * NDIM * 2 * NDIM, NDIM, NDIM);
    transpose_split<<<(NDIM * NFF + 255) / 256, 256, 0, stream>>>(
        W1 + (size_t)l * NDIM * NFF, W1T + (size_t)l * NFF * 2 * NDIM, NDIM, NFF);
    transpose_split<<<(NFF * NDIM + 255) / 256, 256, 0, stream>>>(
        W2 + (size_t)l * NFF * NDIM, W2T + (size_t)l * NDIM * 2 * NFF, NFF, NDIM);
  }

  // ---- layers ----
  for (int l = 0; l < 2; l++) {
    const bf16* WqT_l  = WqT + (size_t)l * NDIM * 2 * NDIM;
    const bf16* WkvT_l = WkvT + (size_t)l * 2 * NDIM * 2 * NDIM;
    const bf16* WoT_l  = WoT + (size_t)l * NDIM * 2 * NDIM;
    const bf16* W1T_l  = W1T + (size_t)l * NFF * 2 * NDIM;
    const bf16* W2T_l  = W2T + (size_t)l * NDIM * 2 * NFF;
    const float* mem_v_l = mem_v + (size_t)l * NHEADS * NMEM * DHEAD;

    ln_kernel<<<NROWS / 4, 256, 0, stream>>>(x, ln1_g + l * NDIM, ln1_b + l * NDIM, hs);
    // Qs = split(0.125 * h @ Wq)   (scale folded)
    gemm_split<128, 128, 2, 2, EPI_SPLIT><<<dim3(NROWS / 128, NDIM / 128, 1), 256, 0, stream>>>(
        hs, WqT_l, Qs, nullptr, NDIM, 2 * NDIM, 2 * NDIM, NDIM, NDIM, NDIM, 0, 0, 0, 0.125f);
    // kv = h @ Wkv  (fp32)
    gemm_split<128, 128, 2, 2, EPI_F32><<<dim3(NROWS / 128, 2 * NDIM / 128, 1), 256, 0, stream>>>(
        hs, WkvT_l, kv, nullptr, NDIM, 2 * NDIM, 2 * NDIM, 2 * NDIM, NDIM, NDIM, 0, 0, 0, 1.0f);
    build_ks<<<(int)(((long long)NB * NJP * NDIM) / 256), 256, 0, stream>>>(
        kv, mem_k + (size_t)l * NHEADS * NMEM * DHEAD, Ks);

    for (int b = 0; b < NB; b++) {
      // per-head raw scores S_h = q_h . k_h  (K=64, z=8 heads via col offset 64)
      gemm_split<128, 128, 2, 2, EPI_F32><<<dim3(NSEQ / 128, NJP / 128, NHEADS), 256, 0, stream>>>(
          Qs + (size_t)b * NSEQ * 2 * NDIM, Ks + (size_t)b * NJP * 2 * NDIM,
          S, nullptr, DHEAD, 2 * NDIM, 2 * NDIM, NJP, NDIM, NDIM,
          DHEAD, DHEAD, PLANE, 1.0f);
      mix_topk_gather<<<NSEQ, 512, 0, stream>>>(
          S, kv, mem_v_l, pre_proj + l * 64, table, obufs, b);
    }

    gemm_split<128, 128, 2, 2, EPI_RESID><<<dim3(NROWS / 128, NDIM / 128, 1), 256, 0, stream>>>(
        obufs, WoT_l, x, bo + l * NDIM, NDIM, 2 * NDIM, 2 * NDIM, NDIM, NDIM, NDIM, 0, 0, 0, 1.0f);

    ln_kernel<<<NROWS / 4, 256, 0, stream>>>(x, ln2_g + l * NDIM, ln2_b + l * NDIM, hs);
    gemm_split<128, 128, 2, 2, EPI_GELUSPLIT><<<dim3(NROWS / 128, NFF / 128, 1), 256, 0, stream>>>(
        hs, W1T_l, tbufs, b1 + l * NFF, NDIM, 2 * NDIM, 2 * NDIM, NFF, NDIM, NDIM, 0, 0, 0, 1.0f);
    gemm_split<128, 128, 2, 2, EPI_RESID><<<dim3(NROWS / 128, NDIM / 128, 1), 256, 0, stream>>>(
        tbufs, W2T_l, x, b2 + l * NDIM, NFF, 2 * NFF, 2 * NFF, NDIM, NFF, NFF, 0, 0, 0, 1.0f);
  }

  hipMemcpyAsync(d_out, x, (size_t)out_size * 4, hipMemcpyDeviceToDevice, stream);
}

// Round 7
// 1021.942 us; speedup vs baseline: 1.7722x; 1.0444x over previous
//
#include <hip/hip_runtime.h>
#include <cmath>

typedef __bf16 bf16;
typedef __attribute__((ext_vector_type(8))) __bf16 bf16x8;
typedef __attribute__((ext_vector_type(4))) __bf16 bf16x4;
typedef __attribute__((ext_vector_type(4))) float f32x4;

#define NB 2
#define NSEQ 2048
#define NDIM 512
#define NHEADS 8
#define DHEAD 64
#define NMEM 16
#define NJ 2064
#define NJP 2176        // 17*128
#define NFF 2048
#define NROWS (NB*NSEQ) // 4096

enum { EPI_F32 = 0, EPI_SPLIT = 1, EPI_GELUSPLIT = 2, EPI_RESID = 3 };

// ---------------------------------------------------------------------------
// Split-precision GEMM: fp32 operands stored as bf16 (hi,lo). hi at col c,
// lo at col c+loA (A) / c+loB (B). C = Ah*Bh + Al*Bh + Ah*Bl, fp32 accum.
// ---------------------------------------------------------------------------
template<int BM, int BN, int WAVES_M, int WAVES_N, int EPI>
__global__ __launch_bounds__(256)
void gemm_split(const bf16* __restrict__ A, const bf16* __restrict__ B,
                void* __restrict__ Cv, const float* __restrict__ bias,
                int K, int lda, int ldb, int ldc, int loA, int loB,
                long long sAz, long long sBz, long long sCz, float scale)
{
  constexpr int BK = 32;
  constexpr int WM = BM / WAVES_M;
  constexpr int WN = BN / WAVES_N;
  constexpr int MF = WM / 16;
  constexpr int NF = WN / 16;
  constexpr int AI = (BM * BK * 2) / 4096;
  constexpr int BI = (BN * BK * 2) / 4096;
  __shared__ bf16 Ash[BM * BK];
  __shared__ bf16 Asl[BM * BK];
  __shared__ bf16 Bsh[BN * BK];
  __shared__ bf16 Bsl[BN * BK];

  const int z = blockIdx.z;
  A += (long long)z * sAz;
  B += (long long)z * sBz;
  const int bm0 = blockIdx.x * BM;
  const int bn0 = blockIdx.y * BN;
  const int t = threadIdx.x;
  const int wave = t >> 6, lane = t & 63;
  const int wr = wave / WAVES_N, wc = wave % WAVES_N;
  const int sr = t >> 2, sc = t & 3;
  const int frow = lane & 15, fk = (lane >> 4) * 8;

  f32x4 acc[MF][NF] = {};

  for (int k0 = 0; k0 < K; k0 += BK) {
#pragma unroll
    for (int qi = 0; qi < AI; ++qi) {
      const long long ro = (long long)(bm0 + qi * 64 + sr) * lda + (k0 + sc * 8);
      __builtin_amdgcn_global_load_lds(
          (const __attribute__((address_space(1))) void*)(A + ro),
          (__attribute__((address_space(3))) void*)(Ash + qi * 2048 + wave * 512), 16, 0, 0);
      __builtin_amdgcn_global_load_lds(
          (const __attribute__((address_space(1))) void*)(A + ro + loA),
          (__attribute__((address_space(3))) void*)(Asl + qi * 2048 + wave * 512), 16, 0, 0);
    }
#pragma unroll
    for (int qi = 0; qi < BI; ++qi) {
      const long long ro = (long long)(bn0 + qi * 64 + sr) * ldb + (k0 + sc * 8);
      __builtin_amdgcn_global_load_lds(
          (const __attribute__((address_space(1))) void*)(B + ro),
          (__attribute__((address_space(3))) void*)(Bsh + qi * 2048 + wave * 512), 16, 0, 0);
      __builtin_amdgcn_global_load_lds(
          (const __attribute__((address_space(1))) void*)(B + ro + loB),
          (__attribute__((address_space(3))) void*)(Bsl + qi * 2048 + wave * 512), 16, 0, 0);
    }
    __syncthreads();
    bf16x8 afh[MF], afl[MF], bfh[NF], bfl[NF];
#pragma unroll
    for (int m = 0; m < MF; m++) {
      afh[m] = *(const bf16x8*)(Ash + (wr * WM + m * 16 + frow) * BK + fk);
      afl[m] = *(const bf16x8*)(Asl + (wr * WM + m * 16 + frow) * BK + fk);
    }
#pragma unroll
    for (int n = 0; n < NF; n++) {
      bfh[n] = *(const bf16x8*)(Bsh + (wc * WN + n * 16 + frow) * BK + fk);
      bfl[n] = *(const bf16x8*)(Bsl + (wc * WN + n * 16 + frow) * BK + fk);
    }
#pragma unroll
    for (int m = 0; m < MF; m++)
#pragma unroll
      for (int n = 0; n < NF; n++) {
        acc[m][n] = __builtin_amdgcn_mfma_f32_16x16x32_bf16(afh[m], bfh[n], acc[m][n], 0, 0, 0);
        acc[m][n] = __builtin_amdgcn_mfma_f32_16x16x32_bf16(afl[m], bfh[n], acc[m][n], 0, 0, 0);
        acc[m][n] = __builtin_amdgcn_mfma_f32_16x16x32_bf16(afh[m], bfl[n], acc[m][n], 0, 0, 0);
      }
    __syncthreads();
  }

  // C/D layout: col=lane&15, row=(lane>>4)*4+reg
#pragma unroll
  for (int m = 0; m < MF; m++) {
#pragma unroll
    for (int n = 0; n < NF; n++) {
      const int row0 = bm0 + wr * WM + m * 16 + (lane >> 4) * 4;
      const int col = bn0 + wc * WN + n * 16 + (lane & 15);
#pragma unroll
      for (int r = 0; r < 4; r++) {
        const float v = acc[m][n][r] * scale;
        const long long i = row0 + r;
        if (EPI == EPI_F32) {
          (((float*)Cv) + z * sCz)[i * (long long)ldc + col] = v;
        } else if (EPI == EPI_SPLIT) {
          bf16* base = ((bf16*)Cv) + z * sCz;
          const long long ih = i * (long long)(2 * ldc) + col;
          bf16 h = (bf16)v;
          base[ih] = h;
          base[ih + ldc] = (bf16)(v - (float)h);
        } else if (EPI == EPI_GELUSPLIT) {
          float u = v + bias[col];
          float gl = 0.5f * u * (1.0f + erff(u * 0.7071067811865476f));
          const long long ih = i * (long long)(2 * ldc) + col;
          bf16 h = (bf16)gl;
          ((bf16*)Cv)[ih] = h;
          ((bf16*)Cv)[ih + ldc] = (bf16)(gl - (float)h);
        } else {  // EPI_RESID
          float* xp = ((float*)Cv) + i * ldc + col;
          *xp = *xp + v + bias[col];
        }
      }
    }
  }
}

// ---------------------------------------------------------------------------
// LayerNorm -> split bf16 (hi | lo), row stride 1024
// ---------------------------------------------------------------------------
__global__ __launch_bounds__(256)
void ln_kernel(const float* __restrict__ x, const float* __restrict__ g,
               const float* __restrict__ b, bf16* __restrict__ out)
{
  const int row = blockIdx.x * 4 + (threadIdx.x >> 6);
  const int lane = threadIdx.x & 63;
  const float* xr = x + (long long)row * NDIM;
  float4 a0 = ((const float4*)xr)[lane];
  float4 a1 = ((const float4*)xr)[lane + 64];
  float s = a0.x + a0.y + a0.z + a0.w + a1.x + a1.y + a1.z + a1.w;
  float ss = a0.x * a0.x + a0.y * a0.y + a0.z * a0.z + a0.w * a0.w
           + a1.x * a1.x + a1.y * a1.y + a1.z * a1.z + a1.w * a1.w;
#pragma unroll
  for (int d = 1; d < 64; d <<= 1) {
    s += __shfl_xor(s, d, 64);
    ss += __shfl_xor(ss, d, 64);
  }
  const float mean = s * (1.0f / NDIM);
  const float var = ss * (1.0f / NDIM) - mean * mean;
  const float rs = rsqrtf(var + 1e-5f);
  float4 g0 = ((const float4*)g)[lane], g1 = ((const float4*)g)[lane + 64];
  float4 b0 = ((const float4*)b)[lane], b1 = ((const float4*)b)[lane + 64];
  bf16* orow = out + (long long)row * (2 * NDIM);
  float y[8] = {
    (a0.x - mean) * rs * g0.x + b0.x, (a0.y - mean) * rs * g0.y + b0.y,
    (a0.z - mean) * rs * g0.z + b0.z, (a0.w - mean) * rs * g0.w + b0.w,
    (a1.x - mean) * rs * g1.x + b1.x, (a1.y - mean) * rs * g1.y + b1.y,
    (a1.z - mean) * rs * g1.z + b1.z, (a1.w - mean) * rs * g1.w + b1.w };
  bf16x4 h0, h1, l0, l1;
#pragma unroll
  for (int j = 0; j < 4; j++) {
    bf16 h = (bf16)y[j];      h0[j] = h;  l0[j] = (bf16)(y[j] - (float)h);
    bf16 h2 = (bf16)y[4 + j]; h1[j] = h2; l1[j] = (bf16)(y[4 + j] - (float)h2);
  }
  *(bf16x4*)(orow + lane * 4) = h0;
  *(bf16x4*)(orow + 256 + lane * 4) = h1;
  *(bf16x4*)(orow + 512 + lane * 4) = l0;
  *(bf16x4*)(orow + 768 + lane * 4) = l1;
}

// ---------------------------------------------------------------------------
// Ks[b][j][c]=hi, [c+512]=lo from kv k-part + mem_k; zero pad rows
// ---------------------------------------------------------------------------
__global__ __launch_bounds__(256)
void build_ks(const float* __restrict__ kv, const float* __restrict__ mem_k_l,
              bf16* __restrict__ Ks)
{
  const long long idx = (long long)blockIdx.x * 256 + threadIdx.x;  // [b][j][c]
  const int c = (int)(idx & 511);
  const int j = (int)((idx >> 9) % NJP);
  const int bb = (int)(idx / ((long long)NJP * NDIM));
  const int h = c >> 6, d = c & 63;
  float kval;
  if (j < NMEM) kval = mem_k_l[(h * NMEM + j) * DHEAD + d];
  else if (j < NJ) kval = kv[(long long)(bb * NSEQ + (j - NMEM)) * (2 * NDIM) + c];
  else kval = 0.f;
  bf16 hv = (bf16)kval;
  const long long ro = ((long long)bb * NJP + j) * (2 * NDIM) + c;
  Ks[ro] = hv;
  Ks[ro + NDIM] = (bf16)(kval - (float)hv);
}

// ---------------------------------------------------------------------------
// Fused talking-heads mix + bias + top-8 + softmax + sparse PV gather.
// S layout is [i][h][j] (interleaved): the 8 plane-rows for row i are one
// contiguous 69.6 KB span. The block stages it into LDS once; all 8 waves
// (one per output head k) mix from LDS. Branchless insertion, values-only
// butterfly, ballot index recovery, fp32 V gather, split-bf16 output.
// ---------------------------------------------------------------------------
__global__ __launch_bounds__(512)
void mix_topk_gather(const float* __restrict__ S, const float* __restrict__ kv,
                     const float* __restrict__ mem_v_l, const float* __restrict__ pp,
                     const float* __restrict__ table, bf16* __restrict__ obufs,
                     int b)
{
  __shared__ float sm[NHEADS * NJP];  // 69632 B
  const int i = blockIdx.x;
  const int k = threadIdx.x >> 6;
  const int lane = threadIdx.x & 63;

  // stage the contiguous [h][j] span for row i
  {
    const float4* src = (const float4*)(S + (long long)i * (NHEADS * NJP));
    float4* dst = (float4*)sm;
    for (int t = threadIdx.x; t < (NHEADS * NJP) / 4; t += 512)
      dst[t] = src[t];
  }
  __syncthreads();

  float pk[8];
#pragma unroll
  for (int h = 0; h < 8; h++) pk[h] = pp[h * 8 + k];

  float v[34];
  float t8[8];
#pragma unroll
  for (int m = 0; m < 8; m++) t8[m] = -3.0e38f;

#pragma unroll
  for (int t = 0; t < 8; t++) {
    const int j0 = 256 * t + 4 * lane;              // j0..j0+3, all < 2048 (valid)
    const float* tb = table + (j0 - i + 2047) * 8 + k;
    float4 a;
    a.x = tb[0]; a.y = tb[8]; a.z = tb[16]; a.w = tb[24];
#pragma unroll
    for (int h = 0; h < 8; h++) {
      const float4 s4 = *(const float4*)(sm + h * NJP + j0);
      a.x = fmaf(s4.x, pk[h], a.x);
      a.y = fmaf(s4.y, pk[h], a.y);
      a.z = fmaf(s4.z, pk[h], a.z);
      a.w = fmaf(s4.w, pk[h], a.w);
    }
    v[t * 4 + 0] = a.x; v[t * 4 + 1] = a.y; v[t * 4 + 2] = a.z; v[t * 4 + 3] = a.w;
    // branchless descending insertion
#pragma unroll
    for (int e = 0; e < 4; e++) {
      float x = v[t * 4 + e];
#pragma unroll
      for (int m = 0; m < 8; m++) {
        const float hi = fmaxf(t8[m], x);
        x = fminf(t8[m], x);
        t8[m] = hi;
      }
    }
  }
  // tail: j = 2048 + 2*lane (+1); valid only for lanes 0..7 (j < 2064)
  {
    const int j0 = 2048 + 2 * lane;
    const int jc = j0 < 2062 ? j0 : 2062;           // keep table reads in-bounds
    const float* tb = table + (jc - i + 2047) * 8 + k;
    float ax = tb[0], ay = tb[8];
#pragma unroll
    for (int h = 0; h < 8; h++) {
      const float2 s2 = *(const float2*)(sm + h * NJP + j0);
      ax = fmaf(s2.x, pk[h], ax);
      ay = fmaf(s2.y, pk[h], ay);
    }
    v[32] = (j0 < NJ) ? ax : -1e30f;
    v[33] = (j0 + 1 < NJ) ? ay : -1e30f;
#pragma unroll
    for (int e = 32; e < 34; e++) {
      float x = v[e];
#pragma unroll
      for (int m = 0; m < 8; m++) {
        const float hi = fmaxf(t8[m], x);
        x = fminf(t8[m], x);
        t8[m] = hi;
      }
    }
  }

  // values-only butterfly: global top-8 (sorted desc) in every lane
#pragma unroll
  for (int d = 1; d < 64; d <<= 1) {
    float o[8], m8[8];
#pragma unroll
    for (int m = 0; m < 8; m++) o[m] = __shfl_xor(t8[m], d, 64);
#pragma unroll
    for (int m = 0; m < 8; m++) m8[m] = fmaxf(t8[m], o[7 - m]);
#define CX(a, bq) { float hi = fmaxf(m8[a], m8[bq]); float lo = fminf(m8[a], m8[bq]); m8[a] = hi; m8[bq] = lo; }
    CX(0, 4) CX(1, 5) CX(2, 6) CX(3, 7)
    CX(0, 2) CX(1, 3) CX(4, 6) CX(5, 7)
    CX(0, 1) CX(2, 3) CX(4, 5) CX(6, 7)
#undef CX
#pragma unroll
    for (int m = 0; m < 8; m++) t8[m] = m8[m];
  }
  const float mx = t8[0];
  const float thr = t8[7];
  float denom = 0.f;
#pragma unroll
  for (int m = 0; m < 8; m++) denom += expf(t8[m] - mx);
  const float inv = 1.0f / denom;

  // index recovery + gather (~8 hits total; ballot loops are wave-uniform)
  float acc = 0.f;
#pragma unroll
  for (int t = 0; t < 8; t++) {
#pragma unroll
    for (int e = 0; e < 4; e++) {
      unsigned long long mball = __ballot(v[t * 4 + e] >= thr);
      while (mball) {
        const int l = __builtin_ctzll(mball);
        mball &= mball - 1;
        const int jj = 256 * t + 4 * l + e;
        const float sv = __shfl(v[t * 4 + e], l);
        const float w = expf(sv - mx) * inv;
        const float vv = (jj < NMEM)
            ? mem_v_l[(k * NMEM + jj) * DHEAD + lane]
            : kv[(long long)(b * NSEQ + (jj - NMEM)) * (2 * NDIM) + NDIM + k * DHEAD + lane];
        acc = fmaf(w, vv, acc);
      }
    }
  }
#pragma unroll
  for (int e = 0; e < 2; e++) {
    unsigned long long mball = __ballot(v[32 + e] >= thr);
    while (mball) {
      const int l = __builtin_ctzll(mball);
      mball &= mball - 1;
      const int jj = 2048 + 2 * l + e;
      const float sv = __shfl(v[32 + e], l);
      const float w = expf(sv - mx) * inv;
      const float vv = (jj < NMEM)
          ? mem_v_l[(k * NMEM + jj) * DHEAD + lane]
          : kv[(long long)(b * NSEQ + (jj - NMEM)) * (2 * NDIM) + NDIM + k * DHEAD + lane];
      acc = fmaf(w, vv, acc);
    }
  }

  const long long orow = (long long)(b * NSEQ + i) * (2 * NDIM) + k * DHEAD + lane;
  bf16 h = (bf16)acc;
  obufs[orow] = h;
  obufs[orow + NDIM] = (bf16)(acc - (float)h);
}

// ---------------------------------------------------------------------------
// fp32 weight (R x C row-major) -> split-transposed bf16 (C x 2R)
// ---------------------------------------------------------------------------
__global__ __launch_bounds__(256)
void transpose_split(const float* __restrict__ in, bf16* __restrict__ out,
                     int R, int C)
{
  const long long idx = (long long)blockIdx.x * 256 + threadIdx.x;
  if (idx >= (long long)R * C) return;
  const int r = (int)(idx / C);
  const int c = (int)(idx % C);
  float v = in[idx];
  bf16 h = (bf16)v;
  out[(long long)c * (2 * R) + r] = h;
  out[(long long)c * (2 * R) + R + r] = (bf16)(v - (float)h);
}

// ---------------------------------------------------------------------------
// T5 bias table; bucket boundaries are exact via log2
// ---------------------------------------------------------------------------
__global__ __launch_bounds__(256)
void build_bias(const float* __restrict__ rel_emb, float* __restrict__ table)
{
  const int idx = blockIdx.x * 256 + threadIdx.x;
  if (idx >= 4111 * 8) return;
  const int h = idx & 7;
  const int rel = (idx >> 3) - 2047;  // rel = j - i
  const int n = -rel;
  const int ret = (n < 0) ? 16 : 0;
  const int na = n < 0 ? -n : n;
  int bucket;
  if (na < 8) {
    bucket = ret + na;
  } else {
    int vl = 8 + (int)(log2((double)na * 0.125) * 2.0);
    vl = vl < 15 ? vl : 15;
    bucket = ret + vl;
  }
  table[idx] = rel_emb[bucket * 8 + h];
}

// ---------------------------------------------------------------------------
extern "C" void kernel_launch(void* const* d_in, const int* in_sizes, int n_in,
                              void* d_out, int out_size, void* d_ws, size_t ws_size,
                              hipStream_t stream)
{
  const float* x_in    = (const float*)d_in[0];
  const float* ln1_g   = (const float*)d_in[1];
  const float* ln1_b   = (const float*)d_in[2];
  const float* Wq      = (const float*)d_in[3];
  const float* Wkv     = (const float*)d_in[4];
  const float* Wo      = (const float*)d_in[5];
  const float* bo      = (const float*)d_in[6];
  const float* pre_proj= (const float*)d_in[7];
  const float* mem_k   = (const float*)d_in[8];
  const float* mem_v   = (const float*)d_in[9];
  const float* ln2_g   = (const float*)d_in[10];
  const float* ln2_b   = (const float*)d_in[11];
  const float* W1      = (const float*)d_in[12];
  const float* b1      = (const float*)d_in[13];
  const float* W2      = (const float*)d_in[14];
  const float* b2      = (const float*)d_in[15];
  const float* rel_emb = (const float*)d_in[16];

  char* p = (char*)d_ws;
  auto alloc = [&](size_t bytes) -> char* {
    char* r = p;
    p += (bytes + 255) & ~(size_t)255;
    return r;
  };

  // ~235 MB total with phase-disjoint aliasing
  float* x    = (float*)alloc((size_t)NROWS * NDIM * 4);          // 8.4 MB
  char*  RA   = alloc((size_t)NROWS * 2 * NDIM * 2);              // 8.4 MB: hs | obufs
  bf16*  hs    = (bf16*)RA;
  bf16*  obufs = (bf16*)RA;
  char*  RB   = alloc((size_t)NROWS * 2 * NFF * 2);               // 33.6 MB: (Qs+Ks) | tbufs
  bf16*  Qs    = (bf16*)RB;                                       // 8.4 MB
  bf16*  Ks    = (bf16*)(RB + (size_t)NROWS * 2 * NDIM * 2);      // 8.9 MB
  bf16*  tbufs = (bf16*)RB;
  float* kv   = (float*)alloc((size_t)NROWS * 2 * NDIM * 4);      // 16.8 MB
  float* S    = (float*)alloc((size_t)NSEQ * NHEADS * NJP * 4);   // 142.6 MB, layout [i][h][j]
  bf16*  WqT  = (bf16*)alloc((size_t)2 * NDIM * 2 * NDIM * 2);
  bf16*  WkvT = (bf16*)alloc((size_t)2 * 2 * NDIM * 2 * NDIM * 2);
  bf16*  WoT  = (bf16*)alloc((size_t)2 * NDIM * 2 * NDIM * 2);
  bf16*  W1T  = (bf16*)alloc((size_t)2 * NFF * 2 * NDIM * 2);
  bf16*  W2T  = (bf16*)alloc((size_t)2 * NDIM * 2 * NFF * 2);
  float* table= (float*)alloc((size_t)4111 * 8 * 4);

  // ---- prep ----
  hipMemcpyAsync(x, x_in, (size_t)NROWS * NDIM * 4, hipMemcpyDeviceToDevice, stream);
  build_bias<<<(4111 * 8 + 255) / 256, 256, 0, stream>>>(rel_emb, table);
  for (int l = 0; l < 2; l++) {
    transpose_split<<<(NDIM * NDIM + 255) / 256, 256, 0, stream>>>(
        Wq + (size_t)l * NDIM * NDIM, WqT + (size_t)l * NDIM * 2 * NDIM, NDIM, NDIM);
    transpose_split<<<(2 * NDIM * NDIM + 255) / 256, 256, 0, stream>>>(
        Wkv + (size_t)l * NDIM * 2 * NDIM, WkvT + (size_t)l * 2 * NDIM * 2 * NDIM, NDIM, 2 * NDIM);
    transpose_split<<<(NDIM * NDIM + 255) / 256, 256, 0, stream>>>(
        Wo + (size_t)l * NDIM * NDIM, WoT + (size_t)l * NDIM * 2 * NDIM, NDIM, NDIM);
    transpose_split<<<(NDIM * NFF + 255) / 256, 256, 0, stream>>>(
        W1 + (size_t)l * NDIM * NFF, W1T + (size_t)l * NFF * 2 * NDIM, NDIM, NFF);
    transpose_split<<<(NFF * NDIM + 255) / 256, 256, 0, stream>>>(
        W2 + (size_t)l * NFF * NDIM, W2T + (size_t)l * NDIM * 2 * NFF, NFF, NDIM);
  }

  // ---- layers ----
  for (int l = 0; l < 2; l++) {
    const bf16* WqT_l  = WqT + (size_t)l * NDIM * 2 * NDIM;
    const bf16* WkvT_l = WkvT + (size_t)l * 2 * NDIM * 2 * NDIM;
    const bf16* WoT_l  = WoT + (size_t)l * NDIM * 2 * NDIM;
    const bf16* W1T_l  = W1T + (size_t)l * NFF * 2 * NDIM;
    const bf16* W2T_l  = W2T + (size_t)l * NDIM * 2 * NFF;
    const float* mem_v_l = mem_v + (size_t)l * NHEADS * NMEM * DHEAD;

    ln_kernel<<<NROWS / 4, 256, 0, stream>>>(x, ln1_g + l * NDIM, ln1_b + l * NDIM, hs);
    // Qs = split(0.125 * h @ Wq)   (scale folded)
    gemm_split<128, 128, 2, 2, EPI_SPLIT><<<dim3(NROWS / 128, NDIM / 128, 1), 256, 0, stream>>>(
        hs, WqT_l, Qs, nullptr, NDIM, 2 * NDIM, 2 * NDIM, NDIM, NDIM, NDIM, 0, 0, 0, 0.125f);
    // kv = h @ Wkv  (fp32)
    gemm_split<128, 128, 2, 2, EPI_F32><<<dim3(NROWS / 128, 2 * NDIM / 128, 1), 256, 0, stream>>>(
        hs, WkvT_l, kv, nullptr, NDIM, 2 * NDIM, 2 * NDIM, 2 * NDIM, NDIM, NDIM, 0, 0, 0, 1.0f);
    build_ks<<<(int)(((long long)NB * NJP * NDIM) / 256), 256, 0, stream>>>(
        kv, mem_k + (size_t)l * NHEADS * NMEM * DHEAD, Ks);

    for (int b = 0; b < NB; b++) {
      // per-head raw scores into S[i][h][j]: ldc = 8*NJP, z-stride = NJP
      gemm_split<128, 128, 2, 2, EPI_F32><<<dim3(NSEQ / 128, NJP / 128, NHEADS), 256, 0, stream>>>(
          Qs + (size_t)b * NSEQ * 2 * NDIM, Ks + (size_t)b * NJP * 2 * NDIM,
          S, nullptr, DHEAD, 2 * NDIM, 2 * NDIM, NHEADS * NJP, NDIM, NDIM,
          DHEAD, DHEAD, NJP, 1.0f);
      mix_topk_gather<<<NSEQ, 512, 0, stream>>>(
          S, kv, mem_v_l, pre_proj + l * 64, table, obufs, b);
    }

    gemm_split<128, 128, 2, 2, EPI_RESID><<<dim3(NROWS / 128, NDIM / 128, 1), 256, 0, stream>>>(
        obufs, WoT_l, x, bo + l * NDIM, NDIM, 2 * NDIM, 2 * NDIM, NDIM, NDIM, NDIM, 0, 0, 0, 1.0f);

    ln_kernel<<<NROWS / 4, 256, 0, stream>>>(x, ln2_g + l * NDIM, ln2_b + l * NDIM, hs);
    gemm_split<128, 128, 2, 2, EPI_GELUSPLIT><<<dim3(NROWS / 128, NFF / 128, 1), 256, 0, stream>>>(
        hs, W1T_l, tbufs, b1 + l * NFF, NDIM, 2 * NDIM, 2 * NDIM, NFF, NDIM, NDIM, 0, 0, 0, 1.0f);
    gemm_split<128, 128, 2, 2, EPI_RESID><<<dim3(NROWS / 128, NDIM / 128, 1), 256, 0, stream>>>(
        tbufs, W2T_l, x, b2 + l * NDIM, NFF, 2 * NFF, 2 * NFF, NDIM, NFF, NFF, 0, 0, 0, 1.0f);
  }

  hipMemcpyAsync(d_out, x, (size_t)out_size * 4, hipMemcpyDeviceToDevice, stream);
}